// Round 8
// baseline (532.893 us; speedup 1.0000x reference)
//
#include <hip/hip_runtime.h>
#include <cstdint>

typedef unsigned short u16;
typedef __bf16 bf16_t;
typedef bf16_t bf16x8 __attribute__((ext_vector_type(8)));
typedef float f32x4 __attribute__((ext_vector_type(4)));

__device__ __forceinline__ float b2f(u16 v) {
  union { uint32_t u; float f; } c; c.u = ((uint32_t)v) << 16; return c.f;
}
__device__ __forceinline__ u16 f2b(float f) {
  union { float f; uint32_t u; } c; c.f = f;
  uint32_t lsb = (c.u >> 16) & 1u;
  return (u16)((c.u + 0x7fffu + lsb) >> 16);
}
__device__ __forceinline__ uint4 pack8(f32x4 a, f32x4 b) {
  union { uint4 v; u16 s[8]; } r;
  r.s[0] = f2b(a[0]); r.s[1] = f2b(a[1]); r.s[2] = f2b(a[2]); r.s[3] = f2b(a[3]);
  r.s[4] = f2b(b[0]); r.s[5] = f2b(b[1]); r.s[6] = f2b(b[2]); r.s[7] = f2b(b[3]);
  return r.v;
}
// packed f32x2 -> bf16x2 (RNE), single instruction (no builtin on gfx950)
__device__ __forceinline__ uint32_t cvt_pk_bf16(float lo, float hi) {
  uint32_t r;
  asm("v_cvt_pk_bf16_f32 %0, %1, %2" : "=v"(r) : "v"(lo), "v"(hi));
  return r;
}
// raw barrier: lgkm drain + s_barrier (no implicit vmcnt drain)
__device__ __forceinline__ void phase_barrier() {
  asm volatile("s_waitcnt lgkmcnt(0)" ::: "memory");
  __builtin_amdgcn_s_barrier();
  asm volatile("" ::: "memory");
}
__device__ __forceinline__ void vm_drain() {
  asm volatile("s_waitcnt vmcnt(0)" ::: "memory");
}
template <int N>
__device__ __forceinline__ void vmwait() {
  asm volatile("s_waitcnt vmcnt(%0)" :: "n"(N) : "memory");
}
// direct global->LDS DMA, 16B per lane. LDS dest: wave-uniform base + lane*16.
__device__ __forceinline__ void gload_lds16(const u16* g, u16* l) {
  __builtin_amdgcn_global_load_lds((const __attribute__((address_space(1))) void*)g,
                                   (__attribute__((address_space(3))) void*)l, 16, 0, 0);
}
// bijective chunked XCD swizzle (m204)
__device__ __forceinline__ int xcd_swizzle(int lid, int nwg) {
  int q = nwg >> 3, r = nwg & 7, x = lid & 7, s = lid >> 3;
  return (x < r ? x * (q + 1) : r * (q + 1) + (x - r) * q) + s;
}

// ---------------- all 5 weight transposes, f32 (R,C) -> bf16 (C,R), one launch ----------------
__global__ __launch_bounds__(256) void transpose_all(
    const float* __restrict__ Wq, const float* __restrict__ Wo, const float* __restrict__ W1,
    const float* __restrict__ W2, const float* __restrict__ Wkv,
    u16* __restrict__ WTq, u16* __restrict__ WTo, u16* __restrict__ WT1,
    u16* __restrict__ WT2, u16* __restrict__ WkvT) {
  __shared__ __align__(16) u16 tile[32][33];
  int bid = blockIdx.x;
  const float* in; u16* out; int R, C, gx, tb;
  if (bid < 576)       { in = Wq;  out = WTq;  R = 768;  C = 768;  gx = 24; tb = bid; }
  else if (bid < 1152) { in = Wo;  out = WTo;  R = 768;  C = 768;  gx = 24; tb = bid - 576; }
  else if (bid < 3456) { in = W1;  out = WT1;  R = 768;  C = 3072; gx = 96; tb = bid - 1152; }
  else if (bid < 5760) { in = W2;  out = WT2;  R = 3072; C = 768;  gx = 24; tb = bid - 3456; }
  else                 { in = Wkv; out = WkvT; R = 768;  C = 128;  gx = 4;  tb = bid - 5760; }
  int c0 = (tb % gx) * 32, r0 = (tb / gx) * 32;
  int tx = threadIdx.x & 31, ty = threadIdx.x >> 5;
#pragma unroll
  for (int i = 0; i < 4; ++i) {
    int r = r0 + ty + i * 8, c = c0 + tx;
    tile[ty + i * 8][tx] = f2b(in[(size_t)r * C + c]);
  }
  __syncthreads();
#pragma unroll
  for (int i = 0; i < 4; ++i) {
    int oc = c0 + ty + i * 8, orr = r0 + tx;
    out[(size_t)oc * R + orr] = tile[tx][ty + i * 8];
  }
}

// ------- LN weight folds for q and w1 (one launch): WgT[n,k]=g[k]*WT[n,k]; u=sum gW; w=sum bW -------
__global__ __launch_bounds__(256) void prep_wg2(
    const u16* __restrict__ WTq, const float* __restrict__ gq, const float* __restrict__ bq_,
    u16* __restrict__ WqgT, float* __restrict__ uq, float* __restrict__ wq,
    const u16* __restrict__ WT1, const float* __restrict__ g1, const float* __restrict__ b1_,
    u16* __restrict__ W1gT, float* __restrict__ u1, float* __restrict__ w1) {
  int bid = blockIdx.x;
  const u16* WT; const float* g; const float* b; u16* WgT; float* u; float* w; int n0;
  if (bid < 192) { WT = WTq; g = gq; b = bq_; WgT = WqgT; u = uq; w = wq; n0 = bid * 4; }
  else { WT = WT1; g = g1; b = b1_; WgT = W1gT; u = u1; w = w1; n0 = (bid - 192) * 4; }
  int n = n0 + (threadIdx.x >> 6);
  int lane = threadIdx.x & 63;
  const u16* src = WT + (size_t)n * 768;
  u16* dst = WgT + (size_t)n * 768;
  float su = 0.f, sw = 0.f;
  for (int k = lane; k < 768; k += 64) {
    float wc = b2f(src[k]);
    float wg = g[k] * wc;
    dst[k] = f2b(wg);
    su += wg;
    sw += b[k] * wc;
  }
#pragma unroll
  for (int off = 32; off >= 1; off >>= 1) {
    su += __shfl_xor(su, off, 64);
    sw += __shfl_xor(sw, off, 64);
  }
  if (lane == 0) { u[n] = su; w[n] = sw; }
}

// ------- img LN weight fold (K=1024, after gemm_wc) -------
__global__ __launch_bounds__(256) void prep_wg(const u16* __restrict__ WT, const float* __restrict__ g,
                                               const float* __restrict__ b, u16* __restrict__ WgT,
                                               float* __restrict__ ucol, float* __restrict__ wcol,
                                               int K) {
  int n = blockIdx.x * 4 + (threadIdx.x >> 6);
  int lane = threadIdx.x & 63;
  const u16* src = WT + (size_t)n * K;
  u16* dst = WgT + (size_t)n * K;
  float su = 0.f, sw = 0.f;
  for (int k = lane; k < K; k += 64) {
    float wc = b2f(src[k]);
    float wg = g[k] * wc;
    dst[k] = f2b(wg);
    su += wg;
    sw += b[k] * wc;
  }
#pragma unroll
  for (int off = 32; off >= 1; off >>= 1) {
    su += __shfl_xor(su, off, 64);
    sw += __shfl_xor(sw, off, 64);
  }
  if (lane == 0) { ucol[n] = su; wcol[n] = sw; }
}

// ------- rowprep (one launch): hs f32->bf16 + stats (2048x768), img f32->bf16 + stats (32768x1024) -------
__global__ __launch_bounds__(256) void rowprep(
    const float* __restrict__ hs, u16* __restrict__ hs16,
    float* __restrict__ rstdq, float* __restrict__ mrstdq,
    const float* __restrict__ img, u16* __restrict__ img16,
    float* __restrict__ rstdi, float* __restrict__ mrstdi) {
  int bid = blockIdx.x, w = threadIdx.x >> 6, lane = threadIdx.x & 63;
  if (bid < 512) {
    int row = bid * 4 + w;
    const float* x = hs + (size_t)row * 768;
    float v[12];
#pragma unroll
    for (int it = 0; it < 3; ++it) {
      f32x4 d = *(const f32x4*)(x + (lane + it * 64) * 4);
      v[it * 4 + 0] = d[0]; v[it * 4 + 1] = d[1]; v[it * 4 + 2] = d[2]; v[it * 4 + 3] = d[3];
    }
    float s = 0.f, s2 = 0.f;
#pragma unroll
    for (int i = 0; i < 12; ++i) { s += v[i]; s2 += v[i] * v[i]; }
#pragma unroll
    for (int off = 32; off >= 1; off >>= 1) {
      s += __shfl_xor(s, off, 64);
      s2 += __shfl_xor(s2, off, 64);
    }
    float inv_n = 1.0f / 768.f;
    float mean = s * inv_n;
    float var = fmaxf(s2 * inv_n - mean * mean, 0.f);
    float rstd = rsqrtf(var + 1e-5f);
    if (lane == 0) { rstdq[row] = rstd; mrstdq[row] = mean * rstd; }
#pragma unroll
    for (int it = 0; it < 3; ++it) {
      int c = (lane + it * 64) * 4;
      uint2 po;
      po.x = (uint32_t)f2b(v[it * 4 + 0]) | ((uint32_t)f2b(v[it * 4 + 1]) << 16);
      po.y = (uint32_t)f2b(v[it * 4 + 2]) | ((uint32_t)f2b(v[it * 4 + 3]) << 16);
      *(uint2*)(hs16 + (size_t)row * 768 + c) = po;
    }
  } else {
    int row = (bid - 512) * 4 + w;
    const float* x = img + (size_t)row * 1024;
    float v[16];
#pragma unroll
    for (int it = 0; it < 4; ++it) {
      f32x4 d = *(const f32x4*)(x + (lane + it * 64) * 4);
      v[it * 4 + 0] = d[0]; v[it * 4 + 1] = d[1]; v[it * 4 + 2] = d[2]; v[it * 4 + 3] = d[3];
    }
    float s = 0.f, s2 = 0.f;
#pragma unroll
    for (int i = 0; i < 16; ++i) { s += v[i]; s2 += v[i] * v[i]; }
#pragma unroll
    for (int off = 32; off >= 1; off >>= 1) {
      s += __shfl_xor(s, off, 64);
      s2 += __shfl_xor(s2, off, 64);
    }
    float inv_n = 1.0f / 1024.f;
    float mean = s * inv_n;
    float var = fmaxf(s2 * inv_n - mean * mean, 0.f);
    float rstd = rsqrtf(var + 1e-5f);
    if (lane == 0) { rstdi[row] = rstd; mrstdi[row] = mean * rstd; }
#pragma unroll
    for (int it = 0; it < 4; ++it) {
      int c = (lane + it * 64) * 4;
      uint2 po;
      po.x = (uint32_t)f2b(v[it * 4 + 0]) | ((uint32_t)f2b(v[it * 4 + 1]) << 16);
      po.y = (uint32_t)f2b(v[it * 4 + 2]) | ((uint32_t)f2b(v[it * 4 + 3]) << 16);
      *(uint2*)(img16 + (size_t)row * 1024 + c) = po;
    }
  }
}

// --- h = hs + sigmoid(gate)*LN(ao): outputs f32 h, bf16 h, per-row LN stats of h ---
__global__ __launch_bounds__(256) void ln_res(const u16* __restrict__ ao, const float* __restrict__ g,
                                              const float* __restrict__ bta,
                                              const float* __restrict__ hs,
                                              const float* __restrict__ gatep,
                                              float* __restrict__ hf, u16* __restrict__ hb,
                                              float* __restrict__ rstdg, float* __restrict__ mrstdg) {
  int row = blockIdx.x * 4 + (threadIdx.x >> 6);
  int lane = threadIdx.x & 63;
  const u16* xb = ao + (size_t)row * 768;
  float v[12];
#pragma unroll
  for (int it = 0; it < 3; ++it) {
    int c = (lane + it * 64) * 4;
    uint2 d = *(const uint2*)(xb + c);
    v[it * 4 + 0] = b2f(d.x & 0xffff); v[it * 4 + 1] = b2f(d.x >> 16);
    v[it * 4 + 2] = b2f(d.y & 0xffff); v[it * 4 + 3] = b2f(d.y >> 16);
  }
  float s = 0.f, s2 = 0.f;
#pragma unroll
  for (int i = 0; i < 12; ++i) { s += v[i]; s2 += v[i] * v[i]; }
#pragma unroll
  for (int off = 32; off >= 1; off >>= 1) {
    s += __shfl_xor(s, off, 64);
    s2 += __shfl_xor(s2, off, 64);
  }
  float inv_n = 1.0f / 768.f;
  float mean = s * inv_n;
  float var = fmaxf(s2 * inv_n - mean * mean, 0.f);
  float rstd = rsqrtf(var + 1e-5f);
  float gate = 1.f / (1.f + __expf(-gatep[0]));
  float hsum = 0.f, hsum2 = 0.f;
  float o[12];
#pragma unroll
  for (int it = 0; it < 3; ++it) {
    int c = (lane + it * 64) * 4;
    const float* rr = hs + (size_t)row * 768 + c;
#pragma unroll
    for (int i = 0; i < 4; ++i) {
      float hv = rr[i] + gate * ((v[it * 4 + i] - mean) * rstd * g[c + i] + bta[c + i]);
      o[it * 4 + i] = hv;
      hsum += hv; hsum2 += hv * hv;
    }
    *(f32x4*)(hf + (size_t)row * 768 + c) = (f32x4){o[it * 4 + 0], o[it * 4 + 1], o[it * 4 + 2], o[it * 4 + 3]};
    uint2 po;
    po.x = (uint32_t)f2b(o[it * 4 + 0]) | ((uint32_t)f2b(o[it * 4 + 1]) << 16);
    po.y = (uint32_t)f2b(o[it * 4 + 2]) | ((uint32_t)f2b(o[it * 4 + 3]) << 16);
    *(uint2*)(hb + (size_t)row * 768 + c) = po;
  }
#pragma unroll
  for (int off = 32; off >= 1; off >>= 1) {
    hsum += __shfl_xor(hsum, off, 64);
    hsum2 += __shfl_xor(hsum2, off, 64);
  }
  float hm = hsum * inv_n;
  float hvar = fmaxf(hsum2 * inv_n - hm * hm, 0.f);
  float hrstd = rsqrtf(hvar + 1e-5f);
  if (lane == 0) { rstdg[row] = hrstd; mrstdg[row] = hm * hrstd; }
}

// ---------------- MFMA GEMM: C = A(MxK)*BT(NxK)^T, BMx128 tile, BK=32 ----------------
// PURE-DMA (AMODE=0,BMODE=0): ring-4 LDS + counted vmcnt. BMODE=1: 2-phase reg staging.
// EPI: 0 none | 1 +bias | 3 LNfold(precomp rstdg/mrstdg)+bias | 5 LNfold(precomp)+bias+gelu.
// VTOUT (kv): C = K-half [M][64] bf16; V-half transposed (via reused ring LDS) to VTout.
template <int BM, int SPLITK, int AMODE, int BMODE, int EPI, bool OUTF32, bool VTOUT>
__device__ __forceinline__ void gemm_body(const void* __restrict__ Av, const void* __restrict__ Bv,
                                          const float* __restrict__ bias,
                                          const float* __restrict__ rstdg,
                                          const float* __restrict__ mrstdg,
                                          const float* __restrict__ ucol,
                                          const float* __restrict__ wcol,
                                          void* __restrict__ Cv, u16* __restrict__ VTout,
                                          int M, int N, int K) {
  constexpr int MT = BM / 32;   // m-tiles per wave
  constexpr int AL = BM / 64;   // DMA loads per thread for A
  constexpr bool PURE = (AMODE == 0 && BMODE == 0);
  constexpr int NBUF = PURE ? 4 : 2;
  constexpr int LPT = AL + 2;   // DMA instrs per thread per tile (pure path)
  __shared__ __align__(16) u16 aT[NBUF][BM * 32];
  __shared__ __align__(16) u16 bT[NBUF][128 * 32];

  int gx = gridDim.x, gy = gridDim.y;
  int nwg = gx * gy * (int)gridDim.z;
  int lid = ((int)blockIdx.z * gy + (int)blockIdx.y) * gx + (int)blockIdx.x;
  int wid = xcd_swizzle(lid, nwg);
  int bz = wid / (gx * gy);
  int rem = wid - bz * (gx * gy);
  int bx = rem / gy;
  int by = rem - bx * gy;

  int t = threadIdx.x, lane = t & 63, wave = t >> 6;
  int quad = lane >> 4, lcol = lane & 15;
  int wm = (wave >> 1) * (16 * MT), wn = (wave & 1) * 64;
  const u16* Ab = (const u16*)Av;
  const u16* Bb = (const u16*)Bv;
  const float* Bf = (const float*)Bv;
  const int kchunk = (SPLITK > 1) ? K / SPLITK : K;
  const int kstart = (SPLITK > 1) ? bz * kchunk : 0;
  int rr = t >> 1, rc = t & 1;  // f32 reg-stage mapping (BMODE=1)
  f32x4 acc[MT][4];
#pragma unroll
  for (int i = 0; i < MT; ++i)
#pragma unroll
    for (int j = 0; j < 4; ++j) acc[i][j] = (f32x4){0.f, 0.f, 0.f, 0.f};

  f32x4 braw[4];

  auto dmaA = [&](int buf, int k0) {
#pragma unroll
    for (int s2 = 0; s2 < AL; ++s2) {
      int row = (wave * AL + s2) * 16 + (lane >> 2);
      int ch = (lane & 3) ^ (row & 3);
      gload_lds16(Ab + (size_t)(bx * BM + row) * K + kstart + k0 + ch * 8,
                  &aT[buf][(wave * AL + s2) * 512]);
    }
  };
  auto dmaB = [&](int buf, int k0) {
#pragma unroll
    for (int s2 = 0; s2 < 2; ++s2) {
      int row = (wave * 2 + s2) * 16 + (lane >> 2);
      int ch = (lane & 3) ^ (row & 3);
      gload_lds16(Bb + (size_t)(by * 128 + row) * K + kstart + k0 + ch * 8,
                  &bT[buf][(wave * 2 + s2) * 512]);
    }
  };
  auto regloadB = [&](int k0) {
    const f32x4* p = (const f32x4*)&Bf[(size_t)(by * 128 + rr) * K + kstart + k0 + rc * 16];
#pragma unroll
    for (int i = 0; i < 4; ++i) braw[i] = p[i];
  };
  auto regstoreB = [&](int buf) {
    uint4 c0 = pack8(braw[0], braw[1]), c1 = pack8(braw[2], braw[3]);
    *(uint4*)&bT[buf][rr * 32 + (((rc * 2 + 0) ^ (rr & 3)) << 3)] = c0;
    *(uint4*)&bT[buf][rr * 32 + (((rc * 2 + 1) ^ (rr & 3)) << 3)] = c1;
  };
  auto compute = [&](int buf) {
    bf16x8 af[MT], bfr[4];
#pragma unroll
    for (int mt = 0; mt < MT; ++mt) {
      int r = wm + mt * 16 + lcol;
      af[mt] = *(const bf16x8*)&aT[buf][r * 32 + (((quad ^ (r & 3))) << 3)];
    }
#pragma unroll
    for (int nt = 0; nt < 4; ++nt) {
      int r = wn + nt * 16 + lcol;
      bfr[nt] = *(const bf16x8*)&bT[buf][r * 32 + (((quad ^ (r & 3))) << 3)];
    }
#pragma unroll
    for (int mt = 0; mt < MT; ++mt)
#pragma unroll
      for (int nt = 0; nt < 4; ++nt)
        acc[mt][nt] = __builtin_amdgcn_mfma_f32_16x16x32_bf16(af[mt], bfr[nt], acc[mt][nt], 0, 0, 0);
  };

  const int nk = kchunk >> 5;
  if (PURE) {
    // ring-4, counted vmcnt: 3 tiles in flight, never drain to 0 mid-loop
    dmaA(0, 0); dmaB(0, 0);
    if (nk > 1) { dmaA(1, 1 << 5); dmaB(1, 1 << 5); }
    if (nk > 2) { dmaA(2, 2 << 5); dmaB(2, 2 << 5); }
    for (int kt = 0; kt < nk; ++kt) {
      int left = nk - 1 - kt;
      if (left >= 2) vmwait<2 * LPT>();
      else if (left == 1) vmwait<LPT>();
      else vmwait<0>();
      phase_barrier();
      if (kt + 3 < nk) { dmaA((kt + 3) & 3, (kt + 3) << 5); dmaB((kt + 3) & 3, (kt + 3) << 5); }
      compute(kt & 3);
    }
  } else {
    // 2-phase reg staging for f32 B (gemm_wc)
    dmaA(0, 0);
    regloadB(0);
    regstoreB(0);
    vm_drain();
    phase_barrier();
    int cur = 0;
    for (int kt = 0; kt < nk; ++kt) {
      bool more = kt + 1 < nk;
      if (more) { dmaA(cur ^ 1, (kt + 1) << 5); regloadB((kt + 1) << 5); }
      compute(cur);
      if (more) regstoreB(cur ^ 1);
      vm_drain();
      phase_barrier();
      cur ^= 1;
    }
  }

  if (VTOUT) {
    // kv: cols 0..63 -> kb[M][64]; cols 64..127 -> transpose via reused ring LDS -> VT[b][d][j]
    __syncthreads();  // all compute ds_reads done before LDS reuse
    u16* vtile = &aT[0][0];  // 64*136 u16 = 17.4 KB <= 32 KB ring A region
    u16* kb = (u16*)Cv;
#pragma unroll
    for (int mt = 0; mt < MT; ++mt) {
#pragma unroll
      for (int nt = 0; nt < 4; ++nt) {
#pragma unroll
        for (int r = 0; r < 4; ++r) {
          int lrow = wm + mt * 16 + quad * 4 + r;
          int row = bx * BM + lrow;
          int col = wn + nt * 16 + lcol;
          float v = rstdg[row] * acc[mt][nt][r] - mrstdg[row] * ucol[col] + wcol[col] + bias[col];
          u16 hv = f2b(v);
          if (wn == 0) kb[(size_t)row * 64 + col] = hv;
          else vtile[(col - 64) * 136 + lrow] = hv;
        }
      }
    }
    __syncthreads();
    int dd = t >> 2, js = (t & 3) * 32;
    int bg = bx >> 5, j0g = (bx & 31) * 128;
    u16* dst = VTout + ((size_t)bg * 64 + dd) * 4096 + j0g + js;
#pragma unroll
    for (int i = 0; i < 4; ++i)
      *(uint4*)(dst + i * 8) = *(const uint4*)&vtile[dd * 136 + js + i * 8];
    return;
  }

  u16* Cb = (u16*)Cv;
  float* Cf = (float*)Cv;
  if (SPLITK > 1) Cf += (size_t)bz * (size_t)M * (size_t)N;
#pragma unroll
  for (int mt = 0; mt < MT; ++mt) {
#pragma unroll
    for (int nt = 0; nt < 4; ++nt) {
#pragma unroll
      for (int r = 0; r < 4; ++r) {
        int lrow = wm + mt * 16 + quad * 4 + r;
        int row = bx * BM + lrow;
        int col = by * 128 + wn + nt * 16 + lcol;
        float v = acc[mt][nt][r];
        if (EPI == 1) v += bias[col];
        if (EPI == 3 || EPI == 5)
          v = rstdg[row] * v - mrstdg[row] * ucol[col] + wcol[col] + bias[col];
        if (EPI == 5) v = 0.5f * v * (1.f + erff(v * 0.70710678118f));
        size_t idx = (size_t)row * N + col;
        if (OUTF32) Cf[idx] = v; else Cb[idx] = f2b(v);
      }
    }
  }
}

// distinct names per call site (rocprof attribution)
#define GEMM_ARGS const void* Av, const void* Bv, const float* bias, const float* rstdg, \
                  const float* mrstdg, const float* ucol, const float* wcol, void* Cv,   \
                  u16* VTout, int M, int N, int K
__global__ __launch_bounds__(256) void gemm_wc(GEMM_ARGS) {
  gemm_body<128, 1, 0, 1, 0, false, false>(Av, Bv, bias, rstdg, mrstdg, ucol, wcol, Cv, VTout, M, N, K);
}
__global__ __launch_bounds__(256) void gemm_kv(GEMM_ARGS) {
  gemm_body<128, 1, 0, 0, 3, false, true>(Av, Bv, bias, rstdg, mrstdg, ucol, wcol, Cv, VTout, M, N, K);
}
__global__ __launch_bounds__(256) void gemm_q(GEMM_ARGS) {
  gemm_body<64, 1, 0, 0, 3, false, false>(Av, Bv, bias, rstdg, mrstdg, ucol, wcol, Cv, VTout, M, N, K);
}
__global__ __launch_bounds__(256) void gemm_o(GEMM_ARGS) {
  gemm_body<64, 1, 0, 0, 1, false, false>(Av, Bv, bias, rstdg, mrstdg, ucol, wcol, Cv, VTout, M, N, K);
}
__global__ __launch_bounds__(256) void gemm_w1(GEMM_ARGS) {
  gemm_body<128, 1, 0, 0, 5, false, false>(Av, Bv, bias, rstdg, mrstdg, ucol, wcol, Cv, VTout, M, N, K);
}
__global__ __launch_bounds__(256) void gemm_w2(GEMM_ARGS) {
  gemm_body<128, 2, 0, 0, 0, true, false>(Av, Bv, bias, rstdg, mrstdg, ucol, wcol, Cv, VTout, M, N, K);
}

// ---------------- split-K merge for W2: out = p0 + p1 + h + b2 ----------------
__global__ __launch_bounds__(256) void w2_merge(const float* __restrict__ part,
                                                const float* __restrict__ hf,
                                                const float* __restrict__ b2,
                                                float* __restrict__ out) {
  int idx = blockIdx.x * 256 + threadIdx.x;
  f32x4 p0 = ((const f32x4*)part)[idx];
  f32x4 p1 = ((const f32x4*)part)[idx + 393216];
  f32x4 h = ((const f32x4*)hf)[idx];
  f32x4 bb = ((const f32x4*)b2)[idx % 192];
  f32x4 o;
#pragma unroll
  for (int i = 0; i < 4; ++i) o[i] = p0[i] + p1[i] + h[i] + bb[i];
  ((f32x4*)out)[idx] = o;
}

// ---------------- flash attention, MQA: 2 heads per block (KV read once per head-pair) ----------------
// grid (4 itiles, 6 head-pairs, 32 = b*4+s). j-split=4.
__global__ __launch_bounds__(256) void attn_kernel(const u16* __restrict__ qbuf,
                                                   const u16* __restrict__ kb,
                                                   const u16* __restrict__ VT,
                                                   float* __restrict__ Opart,
                                                   float* __restrict__ lpart) {
  __shared__ __align__(16) u16 k_lds[2][64 * 72];
  __shared__ __align__(16) u16 vt_lds[2][64 * 72];
  __shared__ __align__(16) u16 p_lds[4 * 16 * 72];
  int lid = ((int)blockIdx.z * 6 + (int)blockIdx.y) * 4 + (int)blockIdx.x;
  int wid = (lid & 7) * 96 + (lid >> 3);  // nwg=768, bijective
  int bi = wid & 3;
  int hp = (wid >> 2) % 6;
  int z = wid / 24;            // 0..31 = b*4+s
  int b = z >> 2, s = z & 3;
  int t = threadIdx.x;
  int wave = t >> 6, lane = t & 63, quad = lane >> 4, lcol = lane & 15;
  int i0 = bi * 64 + wave * 16;
  bf16x8 qf[2][2];
#pragma unroll
  for (int h2 = 0; h2 < 2; ++h2) {
    const u16* qrow = qbuf + ((size_t)(b * 256 + i0 + lcol) * 768 + (hp * 2 + h2) * 64 + quad * 8);
    qf[h2][0] = *(const bf16x8*)qrow;
    qf[h2][1] = *(const bf16x8*)(qrow + 32);
  }
  float l_r[2][4] = {{0.f, 0.f, 0.f, 0.f}, {0.f, 0.f, 0.f, 0.f}};
  f32x4 oacc[2][4];
#pragma unroll
  for (int h2 = 0; h2 < 2; ++h2)
#pragma unroll
    for (int nt = 0; nt < 4; ++nt) oacc[h2][nt] = (f32x4){0.f, 0.f, 0.f, 0.f};
  int sr = t >> 2, sc = (t & 3) * 16;
  const u16* kbase = kb + (size_t)b * 4096 * 64;
  const u16* vtbase = VT + (size_t)b * 64 * 4096;
  u16* pw = &p_lds[wave * 16 * 72];

  uint4 kr0, kr1, vr0, vr1;  // T14 staging regs
  auto stage_load = [&](int jt) {
    int j0 = s * 1024 + jt * 64;
    const u16* krow = kbase + (size_t)(j0 + sr) * 64 + sc;
    kr0 = *(const uint4*)(krow);
    kr1 = *(const uint4*)(krow + 8);
    const u16* vrow = vtbase + (size_t)sr * 4096 + j0 + sc;
    vr0 = *(const uint4*)(vrow);
    vr1 = *(const uint4*)(vrow + 8);
  };
  auto stage_store = [&](int buf) {
    *(uint4*)&k_lds[buf][sr * 72 + sc] = kr0;
    *(uint4*)&k_lds[buf][sr * 72 + sc + 8] = kr1;
    *(uint4*)&vt_lds[buf][sr * 72 + sc] = vr0;
    *(uint4*)&vt_lds[buf][sr * 72 + sc + 8] = vr1;
  };

  stage_load(0);
  stage_store(0);
  phase_barrier();
  int cur = 0;
  for (int jt = 0; jt < 16; ++jt) {
    bool more = jt + 1 < 16;
    if (more) stage_load(jt + 1);  // issue early: hides under 2 heads of compute

#pragma unroll
    for (int h2 = 0; h2 < 2; ++h2) {
      f32x4 sc4[4];
#pragma unroll
      for (int nt = 0; nt < 4; ++nt) sc4[nt] = (f32x4){0.f, 0.f, 0.f, 0.f};
      __builtin_amdgcn_s_setprio(1);
#pragma unroll
      for (int nt = 0; nt < 4; ++nt) {
        bf16x8 kb0 = *(const bf16x8*)&k_lds[cur][(nt * 16 + lcol) * 72 + quad * 8];
        bf16x8 kb1 = *(const bf16x8*)&k_lds[cur][(nt * 16 + lcol) * 72 + 32 + quad * 8];
        sc4[nt] = __builtin_amdgcn_mfma_f32_16x16x32_bf16(qf[h2][0], kb0, sc4[nt], 0, 0, 0);
        sc4[nt] = __builtin_amdgcn_mfma_f32_16x16x32_bf16(qf[h2][1], kb1, sc4[nt], 0, 0, 0);
      }
      __builtin_amdgcn_s_setprio(0);
#pragma unroll
      for (int r = 0; r < 4; ++r) {
        float rsum = 0.f;
#pragma unroll
        for (int nt = 0; nt < 4; ++nt) {
          float p = __expf(sc4[nt][r] * 0.125f);
          sc4[nt][r] = p;
          rsum += p;
        }
        rsum += __shfl_xor(rsum, 1, 64);
        rsum += __shfl_xor(rsum, 2, 64);
        rsum += __shfl_xor(rsum, 4, 64);
        rsum += __shfl_xor(rsum, 8, 64);
        l_r[h2][r] += rsum;
        uint32_t pk01 = cvt_pk_bf16(sc4[0][r], sc4[1][r]);
        uint32_t pk23 = cvt_pk_bf16(sc4[2][r], sc4[3][r]);
        int prow = (quad * 4 + r) * 72 + lcol;
        pw[prow] = (u16)(pk01 & 0xffff);
        pw[prow + 16] = (u16)(pk01 >> 16);
        pw[prow + 32] = (u16)(pk23 & 0xffff);
        pw[prow + 48] = (u16)(pk23 >> 16);
      }
      __builtin_amdgcn_s_setprio(1);
#pragma unroll
      for (int ks = 0; ks < 2; ++ks) {
        bf16x8 pa = *(const bf16x8*)&pw[lcol * 72 + ks * 32 + quad * 8];
#pragma unroll
        for (int nt = 0; nt < 4; ++nt) {
          bf16x8 vb = *(const bf16x8*)&vt_lds[cur][(nt * 16 + lcol) * 72 + ks * 32 + quad * 8];
          oacc[h2][nt] = __builtin_amdgcn_mfma_f32_16x16x32_bf16(pa, vb, oacc[h2][nt], 0, 0, 0);
        }
      }
      __builtin_amdgcn_s_setprio(0);
    }
    if (more) stage_store(cur ^ 1);  // write late
    phase_barrier();
    cur ^= 1;
  }
#pragma unroll
  for (int h2 = 0; h2 < 2; ++h2) {
    size_t base = ((size_t)z * 12 + hp * 2 + h2) * 256;
#pragma unroll
    for (int r = 0; r < 4; ++r) {
      int row = bi * 64 + wave * 16 + quad * 4 + r;
#pragma unroll
      for (int nt = 0; nt < 4; ++nt)
        Opart[(base + row) * 64 + nt * 16 + lcol] = oacc[h2][nt][r];
      if (lcol == 0) lpart[base + row] = l_r[h2][r];
    }
  }
}

// ---------------- merge j-split=4 partials -> attn_o bf16 ----------------
__global__ __launch_bounds__(256) void attn_merge(const float* __restrict__ Opart,
                                                  const float* __restrict__ lpart,
                                                  u16* __restrict__ attn_o) {
  int row = blockIdx.x;
  int col = blockIdx.y * 256 + threadIdx.x;
  int b = row >> 8, i = row & 255, h = col >> 6, d = col & 63;
  float o = 0.f, l = 0.f;
#pragma unroll
  for (int s = 0; s < 4; ++s) {
    size_t ii = (((size_t)(b * 4 + s) * 12 + h) * 256 + i);
    o += Opart[ii * 64 + d];
    l += lpart[ii];
  }
  attn_o[(size_t)row * 768 + col] = f2b(o / l);
}

// ---------------- launch ----------------
extern "C" void kernel_launch(void* const* d_in, const int* in_sizes, int n_in, void* d_out,
                              int out_size, void* d_ws, size_t ws_size, hipStream_t stream) {
  (void)in_sizes; (void)n_in; (void)out_size; (void)ws_size;
  const float* hs = (const float*)d_in[0];
  const float* imgf = (const float*)d_in[1];
  const float* ln_img_g = (const float*)d_in[2];
  const float* ln_img_b = (const float*)d_in[3];
  const float* W_bottle = (const float*)d_in[4];
  const float* ln_h_g = (const float*)d_in[5];
  const float* ln_h_b = (const float*)d_in[6];
  const float* Wq = (const float*)d_in[7];
  const float* bq = (const float*)d_in[8];
  const float* Wkv = (const float*)d_in[9];
  const float* bkv = (const float*)d_in[10];
  const float* Wo = (const float*)d_in[11];
  const float* bo = (const float*)d_in[12];
  const float* ln_ao_g = (const float*)d_in[13];
  const float* ln_ao_b = (const float*)d_in[14];
  const float* gatep = (const float*)d_in[15];
  const float* ln_f_g = (const float*)d_in[16];
  const float* ln_f_b = (const float*)d_in[17];
  const float* W1 = (const float*)d_in[18];
  const float* b1 = (const float*)d_in[19];
  const float* W2 = (const float*)d_in[20];
  const float* b2 = (const float*)d_in[21];

  char* sc = (char*)d_ws;
  auto alloc = [&](size_t bytes) {
    char* p = sc;
    sc += (bytes + 63) & ~(size_t)63;
    return p;
  };
  u16* WTq = (u16*)alloc(768 * 768 * 2);
  u16* WTo = (u16*)alloc(768 * 768 * 2);
  u16* WT1 = (u16*)alloc(3072 * 768 * 2);
  u16* WT2 = (u16*)alloc(768 * 3072 * 2);
  u16* WkvT = (u16*)alloc(128 * 768 * 2);
  u16* WcT = (u16*)alloc(128 * 1024 * 2);
  u16* WgT = (u16*)alloc(128 * 1024 * 2);
  u16* WqgT = (u16*)alloc(768 * 768 * 2);
  u16* W1gT = (u16*)alloc(3072 * 768 * 2);
  float* ucol = (float*)alloc(128 * 4);
  float* wcol = (float*)alloc(128 * 4);
  float* uq = (float*)alloc(768 * 4);
  float* wq = (float*)alloc(768 * 4);
  float* u1 = (float*)alloc(3072 * 4);
  float* w1c = (float*)alloc(3072 * 4);
  float* rstdq = (float*)alloc(2048 * 4);
  float* mrstdq = (float*)alloc(2048 * 4);
  float* rstdh = (float*)alloc(2048 * 4);
  float* mrstdh = (float*)alloc(2048 * 4);
  float* rstdi = (float*)alloc(32768 * 4);
  float* mrstdi = (float*)alloc(32768 * 4);
  u16* hs16 = (u16*)alloc(2048 * 768 * 2);
  u16* img16 = (u16*)alloc((size_t)32768 * 1024 * 2);
  u16* kb = (u16*)alloc((size_t)32768 * 64 * 2);
  u16* VT = (u16*)alloc((size_t)8 * 64 * 4096 * 2);
  u16* qb = (u16*)alloc(2048 * 768 * 2);
  u16* attn_o = (u16*)alloc(2048 * 768 * 2);
  u16* ao = (u16*)alloc(2048 * 768 * 2);
  u16* hbuf = (u16*)alloc(2048 * 768 * 2);
  float* hf32 = (float*)alloc(2048 * 768 * 4);
  u16* actb = (u16*)alloc((size_t)2048 * 3072 * 2);
  float* Opart = (float*)alloc((size_t)32 * 12 * 256 * 64 * 4);  // also W2 split-K partials
  float* lpart = (float*)alloc((size_t)32 * 12 * 256 * 4);

  // 1. all weight transposes (one launch)
  transpose_all<<<5856, 256, 0, stream>>>(Wq, Wo, W1, W2, Wkv, WTq, WTo, WT1, WT2, WkvT);
  // 2. LN weight folds for q and w1 (one launch)
  prep_wg2<<<960, 256, 0, stream>>>(WTq, ln_h_g, ln_h_b, WqgT, uq, wq,
                                    WT1, ln_f_g, ln_f_b, W1gT, u1, w1c);
  // 3. WcT[n,kimg] = sum_j WkvT[n,j] * W_bottle[kimg,j]
  gemm_wc<<<dim3(1, 8), 256, 0, stream>>>(WkvT, W_bottle, nullptr, nullptr, nullptr, nullptr,
                                          nullptr, WcT, nullptr, 128, 1024, 768);
  // 4. img LN weight fold
  prep_wg<<<32, 256, 0, stream>>>(WcT, ln_img_g, ln_img_b, WgT, ucol, wcol, 1024);
  // 5. hs + img -> bf16 + per-row LN stats (one launch)
  rowprep<<<8704, 256, 0, stream>>>(hs, hs16, rstdq, mrstdq, imgf, img16, rstdi, mrstdi);
  // 6. kv (folded img-LN, pure-DMA ring) -> kb + VT
  gemm_kv<<<dim3(256, 1), 256, 0, stream>>>(img16, WgT, bkv, rstdi, mrstdi, ucol, wcol,
                                            kb, VT, 32768, 128, 1024);
  // 7. q = LN(hs) @ Wq + bq  (folded)
  gemm_q<<<dim3(32, 6), 256, 0, stream>>>(hs16, WqgT, bq, rstdq, mrstdq, uq, wq,
                                          qb, nullptr, 2048, 768, 768);
  // 8. attention (2 heads/block, j-split=4)
  attn_kernel<<<dim3(4, 6, 32), 256, 0, stream>>>(qb, kb, VT, Opart, lpart);
  // 9. merge partials
  attn_merge<<<dim3(2048, 3), 256, 0, stream>>>(Opart, lpart, attn_o);
  // 10. out proj
  gemm_o<<<dim3(32, 6), 256, 0, stream>>>(attn_o, WTo, bo, nullptr, nullptr, nullptr, nullptr,
                                          ao, nullptr, 2048, 768, 768);
  // 11. h = hs + sigmoid(gate)*LN(ao): f32 + bf16 + h-stats
  ln_res<<<512, 256, 0, stream>>>(ao, ln_ao_g, ln_ao_b, hs, gatep, hf32, hbuf, rstdh, mrstdh);
  // 12. act = gelu(LN(h) @ W1 + b1)  (folded)
  gemm_w1<<<dim3(16, 24), 256, 0, stream>>>(hbuf, W1gT, b1, rstdh, mrstdh, u1, w1c,
                                            actb, nullptr, 2048, 3072, 768);
  // 13. W2 split-K=2 partials (BM=128) into Opart
  gemm_w2<<<dim3(16, 6, 2), 256, 0, stream>>>(actb, WT2, nullptr, nullptr, nullptr, nullptr, nullptr,
                                              Opart, nullptr, 2048, 768, 3072);
  // 14. final merge
  w2_merge<<<1536, 256, 0, stream>>>(Opart, hf32, b2, (float*)d_out);
}

// Round 10
// 495.253 us; speedup vs baseline: 1.0760x; 1.0760x over previous
//
#include <hip/hip_runtime.h>
#include <cstdint>

typedef unsigned short u16;
typedef __bf16 bf16_t;
typedef bf16_t bf16x8 __attribute__((ext_vector_type(8)));
typedef float f32x4 __attribute__((ext_vector_type(4)));

__device__ __forceinline__ float b2f(u16 v) {
  union { uint32_t u; float f; } c; c.u = ((uint32_t)v) << 16; return c.f;
}
__device__ __forceinline__ u16 f2b(float f) {
  union { float f; uint32_t u; } c; c.f = f;
  uint32_t lsb = (c.u >> 16) & 1u;
  return (u16)((c.u + 0x7fffu + lsb) >> 16);
}
__device__ __forceinline__ uint4 pack8(f32x4 a, f32x4 b) {
  union { uint4 v; u16 s[8]; } r;
  r.s[0] = f2b(a[0]); r.s[1] = f2b(a[1]); r.s[2] = f2b(a[2]); r.s[3] = f2b(a[3]);
  r.s[4] = f2b(b[0]); r.s[5] = f2b(b[1]); r.s[6] = f2b(b[2]); r.s[7] = f2b(b[3]);
  return r.v;
}
__device__ __forceinline__ uint32_t cvt_pk_bf16(float lo, float hi) {
  uint32_t r;
  asm("v_cvt_pk_bf16_f32 %0, %1, %2" : "=v"(r) : "v"(lo), "v"(hi));
  return r;
}
__device__ __forceinline__ void phase_barrier() {
  asm volatile("s_waitcnt lgkmcnt(0)" ::: "memory");
  __builtin_amdgcn_s_barrier();
  asm volatile("" ::: "memory");
}
__device__ __forceinline__ void vm_drain() {
  asm volatile("s_waitcnt vmcnt(0)" ::: "memory");
}
template <int N>
__device__ __forceinline__ void vmwait() {
  asm volatile("s_waitcnt vmcnt(%0)" :: "n"(N) : "memory");
}
__device__ __forceinline__ void gload_lds16(const u16* g, u16* l) {
  __builtin_amdgcn_global_load_lds((const __attribute__((address_space(1))) void*)g,
                                   (__attribute__((address_space(3))) void*)l, 16, 0, 0);
}
// bijective chunked XCD swizzle (m204)
__device__ __forceinline__ int xcd_swizzle(int lid, int nwg) {
  int q = nwg >> 3, r = nwg & 7, x = lid & 7, s = lid >> 3;
  return (x < r ? x * (q + 1) : r * (q + 1) + (x - r) * q) + s;
}

// ========== prep_main: 5 transposes + hs/img rowprep (all read only kernel inputs) ==========
__global__ __launch_bounds__(256) void prep_main(
    const float* __restrict__ Wq, const float* __restrict__ Wo, const float* __restrict__ W1,
    const float* __restrict__ W2, const float* __restrict__ Wkv,
    u16* __restrict__ WTq, u16* __restrict__ WTo, u16* __restrict__ WT1,
    u16* __restrict__ WT2, u16* __restrict__ WkvT,
    const float* __restrict__ hs, u16* __restrict__ hs16,
    float* __restrict__ rstdq, float* __restrict__ mrstdq,
    const float* __restrict__ img, u16* __restrict__ img16,
    float* __restrict__ rstdi, float* __restrict__ mrstdi) {
  __shared__ __align__(16) u16 tile[32][33];
  int bid = blockIdx.x;
  int lane = threadIdx.x & 63, w = threadIdx.x >> 6;
  if (bid < 5856) {
    // ---- transposes f32 (R,C) -> bf16 (C,R) ----
    const float* in; u16* out; int R, C, gx, tb;
    if (bid < 576)       { in = Wq;  out = WTq;  R = 768;  C = 768;  gx = 24; tb = bid; }
    else if (bid < 1152) { in = Wo;  out = WTo;  R = 768;  C = 768;  gx = 24; tb = bid - 576; }
    else if (bid < 3456) { in = W1;  out = WT1;  R = 768;  C = 3072; gx = 96; tb = bid - 1152; }
    else if (bid < 5760) { in = W2;  out = WT2;  R = 3072; C = 768;  gx = 24; tb = bid - 3456; }
    else                 { in = Wkv; out = WkvT; R = 768;  C = 128;  gx = 4;  tb = bid - 5760; }
    int c0 = (tb % gx) * 32, r0 = (tb / gx) * 32;
    int tx = threadIdx.x & 31, ty = threadIdx.x >> 5;
#pragma unroll
    for (int i = 0; i < 4; ++i) {
      int r = r0 + ty + i * 8, c = c0 + tx;
      tile[ty + i * 8][tx] = f2b(in[(size_t)r * C + c]);
    }
    __syncthreads();
#pragma unroll
    for (int i = 0; i < 4; ++i) {
      int oc = c0 + ty + i * 8, orr = r0 + tx;
      out[(size_t)oc * R + orr] = tile[tx][ty + i * 8];
    }
  } else if (bid < 6368) {
    // ---- hs f32->bf16 + per-row LN stats ----
    int row = (bid - 5856) * 4 + w;
    const float* x = hs + (size_t)row * 768;
    float v[12];
#pragma unroll
    for (int it = 0; it < 3; ++it) {
      f32x4 d = *(const f32x4*)(x + (lane + it * 64) * 4);
      v[it * 4 + 0] = d[0]; v[it * 4 + 1] = d[1]; v[it * 4 + 2] = d[2]; v[it * 4 + 3] = d[3];
    }
    float s = 0.f, s2 = 0.f;
#pragma unroll
    for (int i = 0; i < 12; ++i) { s += v[i]; s2 += v[i] * v[i]; }
#pragma unroll
    for (int off = 32; off >= 1; off >>= 1) {
      s += __shfl_xor(s, off, 64);
      s2 += __shfl_xor(s2, off, 64);
    }
    float inv_n = 1.0f / 768.f;
    float mean = s * inv_n;
    float var = fmaxf(s2 * inv_n - mean * mean, 0.f);
    float rstd = rsqrtf(var + 1e-5f);
    if (lane == 0) { rstdq[row] = rstd; mrstdq[row] = mean * rstd; }
#pragma unroll
    for (int it = 0; it < 3; ++it) {
      int c = (lane + it * 64) * 4;
      uint2 po;
      po.x = (uint32_t)f2b(v[it * 4 + 0]) | ((uint32_t)f2b(v[it * 4 + 1]) << 16);
      po.y = (uint32_t)f2b(v[it * 4 + 2]) | ((uint32_t)f2b(v[it * 4 + 3]) << 16);
      *(uint2*)(hs16 + (size_t)row * 768 + c) = po;
    }
  } else {
    // ---- img f32->bf16 + per-row LN stats (32768 rows) ----
    int row = (bid - 6368) * 4 + w;
    const float* x = img + (size_t)row * 1024;
    float v[16];
#pragma unroll
    for (int it = 0; it < 4; ++it) {
      f32x4 d = *(const f32x4*)(x + (lane + it * 64) * 4);
      v[it * 4 + 0] = d[0]; v[it * 4 + 1] = d[1]; v[it * 4 + 2] = d[2]; v[it * 4 + 3] = d[3];
    }
    float s = 0.f, s2 = 0.f;
#pragma unroll
    for (int i = 0; i < 16; ++i) { s += v[i]; s2 += v[i] * v[i]; }
#pragma unroll
    for (int off = 32; off >= 1; off >>= 1) {
      s += __shfl_xor(s, off, 64);
      s2 += __shfl_xor(s2, off, 64);
    }
    float inv_n = 1.0f / 1024.f;
    float mean = s * inv_n;
    float var = fmaxf(s2 * inv_n - mean * mean, 0.f);
    float rstd = rsqrtf(var + 1e-5f);
    if (lane == 0) { rstdi[row] = rstd; mrstdi[row] = mean * rstd; }
#pragma unroll
    for (int it = 0; it < 4; ++it) {
      int c = (lane + it * 64) * 4;
      uint2 po;
      po.x = (uint32_t)f2b(v[it * 4 + 0]) | ((uint32_t)f2b(v[it * 4 + 1]) << 16);
      po.y = (uint32_t)f2b(v[it * 4 + 2]) | ((uint32_t)f2b(v[it * 4 + 3]) << 16);
      *(uint2*)(img16 + (size_t)row * 1024 + c) = po;
    }
  }
}

// ====== prep_fold: q/w1 LN weight folds (reads prep_main outputs — SEPARATE launch) ======
__global__ __launch_bounds__(256) void prep_fold(
    const u16* __restrict__ WTq, const float* __restrict__ gq, const float* __restrict__ bq_,
    u16* __restrict__ WqgT, float* __restrict__ uq, float* __restrict__ wqv,
    const u16* __restrict__ WT1, const float* __restrict__ g1, const float* __restrict__ b1_,
    u16* __restrict__ W1gT, float* __restrict__ u1, float* __restrict__ w1v) {
  int pid = blockIdx.x;
  int lane = threadIdx.x & 63, w = threadIdx.x >> 6;
  const u16* WT; const float* g; const float* b; u16* WgT; float* u; float* wv; int n0;
  if (pid < 192) { WT = WTq; g = gq; b = bq_; WgT = WqgT; u = uq; wv = wqv; n0 = pid * 4; }
  else { WT = WT1; g = g1; b = b1_; WgT = W1gT; u = u1; wv = w1v; n0 = (pid - 192) * 4; }
  int n = n0 + w;
  const u16* src = WT + (size_t)n * 768;
  u16* dst = WgT + (size_t)n * 768;
  float su = 0.f, sw = 0.f;
  for (int k = lane; k < 768; k += 64) {
    float wc = b2f(src[k]);
    float wg = g[k] * wc;
    dst[k] = f2b(wg);
    su += wg;
    sw += b[k] * wc;
  }
#pragma unroll
  for (int off = 32; off >= 1; off >>= 1) {
    su += __shfl_xor(su, off, 64);
    sw += __shfl_xor(sw, off, 64);
  }
  if (lane == 0) { u[n] = su; wv[n] = sw; }
}

// ------- img LN weight fold (K=1024, after gemm_wc) -------
__global__ __launch_bounds__(256) void prep_wg(const u16* __restrict__ WT, const float* __restrict__ g,
                                               const float* __restrict__ b, u16* __restrict__ WgT,
                                               float* __restrict__ ucol, float* __restrict__ wcol,
                                               int K) {
  int n = blockIdx.x * 4 + (threadIdx.x >> 6);
  int lane = threadIdx.x & 63;
  const u16* src = WT + (size_t)n * K;
  u16* dst = WgT + (size_t)n * K;
  float su = 0.f, sw = 0.f;
  for (int k = lane; k < K; k += 64) {
    float wc = b2f(src[k]);
    float wg = g[k] * wc;
    dst[k] = f2b(wg);
    su += wg;
    sw += b[k] * wc;
  }
#pragma unroll
  for (int off = 32; off >= 1; off >>= 1) {
    su += __shfl_xor(su, off, 64);
    sw += __shfl_xor(sw, off, 64);
  }
  if (lane == 0) { ucol[n] = su; wcol[n] = sw; }
}

// --- h = hs + sigmoid(gate)*LN(ao): outputs f32 h, bf16 h, per-row LN stats of h ---
__global__ __launch_bounds__(256) void ln_res(const u16* __restrict__ ao, const float* __restrict__ g,
                                              const float* __restrict__ bta,
                                              const float* __restrict__ hs,
                                              const float* __restrict__ gatep,
                                              float* __restrict__ hf, u16* __restrict__ hb,
                                              float* __restrict__ rstdg, float* __restrict__ mrstdg) {
  int row = blockIdx.x * 4 + (threadIdx.x >> 6);
  int lane = threadIdx.x & 63;
  const u16* xb = ao + (size_t)row * 768;
  float v[12];
#pragma unroll
  for (int it = 0; it < 3; ++it) {
    int c = (lane + it * 64) * 4;
    uint2 d = *(const uint2*)(xb + c);
    v[it * 4 + 0] = b2f(d.x & 0xffff); v[it * 4 + 1] = b2f(d.x >> 16);
    v[it * 4 + 2] = b2f(d.y & 0xffff); v[it * 4 + 3] = b2f(d.y >> 16);
  }
  float s = 0.f, s2 = 0.f;
#pragma unroll
  for (int i = 0; i < 12; ++i) { s += v[i]; s2 += v[i] * v[i]; }
#pragma unroll
  for (int off = 32; off >= 1; off >>= 1) {
    s += __shfl_xor(s, off, 64);
    s2 += __shfl_xor(s2, off, 64);
  }
  float inv_n = 1.0f / 768.f;
  float mean = s * inv_n;
  float var = fmaxf(s2 * inv_n - mean * mean, 0.f);
  float rstd = rsqrtf(var + 1e-5f);
  float gate = 1.f / (1.f + __expf(-gatep[0]));
  float hsum = 0.f, hsum2 = 0.f;
  float o[12];
#pragma unroll
  for (int it = 0; it < 3; ++it) {
    int c = (lane + it * 64) * 4;
    const float* rr = hs + (size_t)row * 768 + c;
#pragma unroll
    for (int i = 0; i < 4; ++i) {
      float hv = rr[i] + gate * ((v[it * 4 + i] - mean) * rstd * g[c + i] + bta[c + i]);
      o[it * 4 + i] = hv;
      hsum += hv; hsum2 += hv * hv;
    }
    *(f32x4*)(hf + (size_t)row * 768 + c) = (f32x4){o[it * 4 + 0], o[it * 4 + 1], o[it * 4 + 2], o[it * 4 + 3]};
    uint2 po;
    po.x = (uint32_t)f2b(o[it * 4 + 0]) | ((uint32_t)f2b(o[it * 4 + 1]) << 16);
    po.y = (uint32_t)f2b(o[it * 4 + 2]) | ((uint32_t)f2b(o[it * 4 + 3]) << 16);
    *(uint2*)(hb + (size_t)row * 768 + c) = po;
  }
#pragma unroll
  for (int off = 32; off >= 1; off >>= 1) {
    hsum += __shfl_xor(hsum, off, 64);
    hsum2 += __shfl_xor(hsum2, off, 64);
  }
  float hm = hsum * inv_n;
  float hvar = fmaxf(hsum2 * inv_n - hm * hm, 0.f);
  float hrstd = rsqrtf(hvar + 1e-5f);
  if (lane == 0) { rstdg[row] = hrstd; mrstdg[row] = hm * hrstd; }
}

// ================= MFMA GEMM body: C = A(MxK)*BT(NxK)^T, BMx128 tile, BK=32 =================
// LDS caller-provided; virtual grid allows multiple GEMMs per launch.
// AMODE: 0 bf16-DMA | 2 attn-merge-A (4-way Opart + lpart). BMODE: 0 bf16-DMA | 1 f32-reg.
// PURE(=both DMA): ring-4 + counted vmcnt; else 2-phase.
// EPI: 0 none | 1 +bias | 3 LNfold(precomp)+bias | 5 LNfold+bias+gelu. VTOUT: kv K/V split.
template <int BM, int SPLITK, int AMODE, int BMODE, int EPI, bool OUTF32, bool VTOUT>
__device__ __forceinline__ void gemm_body(u16* __restrict__ aTb, u16* __restrict__ bTb,
                                          const void* __restrict__ Av, const void* __restrict__ Bv,
                                          const float* __restrict__ bias,
                                          const float* __restrict__ rstdg,
                                          const float* __restrict__ mrstdg,
                                          const float* __restrict__ ucol,
                                          const float* __restrict__ wcol,
                                          const float* __restrict__ auxl,
                                          void* __restrict__ Cv, u16* __restrict__ VTout,
                                          int M, int N, int K,
                                          int vgx, int vgy, int vgz, int vlid) {
  constexpr int MT = BM / 32;
  constexpr int AL = BM / 64;
  constexpr bool PURE = (AMODE == 0 && BMODE == 0);
  constexpr int LPT = AL + 2;
  constexpr int ASZ = BM * 32;
  constexpr int BSZ = 128 * 32;

  int nwg = vgx * vgy * vgz;
  int wid = xcd_swizzle(vlid, nwg);
  int bz = wid / (vgx * vgy);
  int rem = wid - bz * (vgx * vgy);
  int bx = rem / vgy;
  int by = rem - bx * vgy;

  int t = threadIdx.x, lane = t & 63, wave = t >> 6;
  int quad = lane >> 4, lcol = lane & 15;
  int wm = (wave >> 1) * (16 * MT), wn = (wave & 1) * 64;
  const u16* Ab = (const u16*)Av;
  const float* Af = (const float*)Av;
  const u16* Bb = (const u16*)Bv;
  const float* Bf = (const float*)Bv;
  const int kchunk = (SPLITK > 1) ? K / SPLITK : K;
  const int kstart = (SPLITK > 1) ? bz * kchunk : 0;
  int rr = t >> 1, rc = t & 1;  // f32 B reg-stage mapping
  f32x4 acc[MT][4];
#pragma unroll
  for (int i = 0; i < MT; ++i)
#pragma unroll
    for (int j = 0; j < 4; ++j) acc[i][j] = (f32x4){0.f, 0.f, 0.f, 0.f};

  f32x4 braw[4];
  f32x4 am0, am1;  // AMODE=2 staging

  auto dmaA = [&](int buf, int k0) {
#pragma unroll
    for (int s2 = 0; s2 < AL; ++s2) {
      int row = (wave * AL + s2) * 16 + (lane >> 2);
      int ch = (lane & 3) ^ (row & 3);
      gload_lds16(Ab + (size_t)(bx * BM + row) * K + kstart + k0 + ch * 8,
                  aTb + buf * ASZ + (wave * AL + s2) * 512);
    }
  };
  auto dmaB = [&](int buf, int k0) {
#pragma unroll
    for (int s2 = 0; s2 < 2; ++s2) {
      int row = (wave * 2 + s2) * 16 + (lane >> 2);
      int ch = (lane & 3) ^ (row & 3);
      gload_lds16(Bb + (size_t)(by * 128 + row) * K + kstart + k0 + ch * 8,
                  bTb + buf * BSZ + (wave * 2 + s2) * 512);
    }
  };
  // AMODE=2 (BM=64): A[row][c] = sum_s Opart / sum_s lpart; 8 cols/thread
  auto loadAmerge = [&](int k0) {
    int c0 = kstart + k0 + (t & 3) * 8;
    int hh = c0 >> 6, dd = c0 & 63;
    int row = bx * 64 + (t >> 2);
    int bb = row >> 8, ii = row & 255;
    am0 = (f32x4){0.f, 0.f, 0.f, 0.f};
    am1 = (f32x4){0.f, 0.f, 0.f, 0.f};
    float lsum = 0.f;
#pragma unroll
    for (int s = 0; s < 4; ++s) {
      size_t base = ((size_t)((bb * 4 + s) * 12 + hh)) * 256 + ii;
      const f32x4* p = (const f32x4*)(Af + base * 64 + dd);
      f32x4 p0 = p[0], p1 = p[1];
#pragma unroll
      for (int j = 0; j < 4; ++j) { am0[j] += p0[j]; am1[j] += p1[j]; }
      lsum += auxl[base];
    }
    float rl = 1.f / lsum;
#pragma unroll
    for (int j = 0; j < 4; ++j) { am0[j] *= rl; am1[j] *= rl; }
  };
  auto storeAmerge = [&](int buf) {
    uint4 c = pack8(am0, am1);
    int ar = t >> 2, ch = t & 3;
    *(uint4*)(aTb + buf * ASZ + ar * 32 + ((ch ^ (ar & 3)) << 3)) = c;
  };
  auto regloadB = [&](int k0) {
    const f32x4* p = (const f32x4*)&Bf[(size_t)(by * 128 + rr) * K + kstart + k0 + rc * 16];
#pragma unroll
    for (int i = 0; i < 4; ++i) braw[i] = p[i];
  };
  auto regstoreB = [&](int buf) {
    uint4 c0 = pack8(braw[0], braw[1]), c1 = pack8(braw[2], braw[3]);
    *(uint4*)(bTb + buf * BSZ + rr * 32 + (((rc * 2 + 0) ^ (rr & 3)) << 3)) = c0;
    *(uint4*)(bTb + buf * BSZ + rr * 32 + (((rc * 2 + 1) ^ (rr & 3)) << 3)) = c1;
  };
  auto compute = [&](int buf) {
    bf16x8 af[MT], bfr[4];
#pragma unroll
    for (int mt = 0; mt < MT; ++mt) {
      int r = wm + mt * 16 + lcol;
      af[mt] = *(const bf16x8*)(aTb + buf * ASZ + r * 32 + (((quad ^ (r & 3))) << 3));
    }
#pragma unroll
    for (int nt = 0; nt < 4; ++nt) {
      int r = wn + nt * 16 + lcol;
      bfr[nt] = *(const bf16x8*)(bTb + buf * BSZ + r * 32 + (((quad ^ (r & 3))) << 3));
    }
#pragma unroll
    for (int mt = 0; mt < MT; ++mt)
#pragma unroll
      for (int nt = 0; nt < 4; ++nt)
        acc[mt][nt] = __builtin_amdgcn_mfma_f32_16x16x32_bf16(af[mt], bfr[nt], acc[mt][nt], 0, 0, 0);
  };

  const int nk = kchunk >> 5;
  if (PURE) {
    // ring-4 + counted vmcnt: 3 tiles in flight, never drain mid-loop
    dmaA(0, 0); dmaB(0, 0);
    if (nk > 1) { dmaA(1, 1 << 5); dmaB(1, 1 << 5); }
    if (nk > 2) { dmaA(2, 2 << 5); dmaB(2, 2 << 5); }
    for (int kt = 0; kt < nk; ++kt) {
      int left = nk - 1 - kt;
      if (left >= 2) vmwait<2 * LPT>();
      else if (left == 1) vmwait<LPT>();
      else vmwait<0>();
      phase_barrier();
      if (kt + 3 < nk) { dmaA((kt + 3) & 3, (kt + 3) << 5); dmaB((kt + 3) & 3, (kt + 3) << 5); }
      compute(kt & 3);
    }
  } else {
    // 2-phase: reg-staged operand(s) + DMA others
    if (AMODE == 2) loadAmerge(0); else dmaA(0, 0);
    if (BMODE == 1) regloadB(0); else dmaB(0, 0);
    if (AMODE == 2) storeAmerge(0);
    if (BMODE == 1) regstoreB(0);
    vm_drain();
    phase_barrier();
    int cur = 0;
    for (int kt = 0; kt < nk; ++kt) {
      bool more = kt + 1 < nk;
      if (more) {
        if (AMODE == 2) loadAmerge((kt + 1) << 5); else dmaA(cur ^ 1, (kt + 1) << 5);
        if (BMODE == 1) regloadB((kt + 1) << 5); else dmaB(cur ^ 1, (kt + 1) << 5);
      }
      compute(cur);
      if (more) {
        if (AMODE == 2) storeAmerge(cur ^ 1);
        if (BMODE == 1) regstoreB(cur ^ 1);
      }
      vm_drain();
      phase_barrier();
      cur ^= 1;
    }
  }

  if (VTOUT) {
    // kv: cols 0..63 -> kb[M][64]; cols 64..127 -> transpose via reused LDS -> VT[b][d][j]
    __syncthreads();
    u16* vtile = aTb;  // 64*136 u16 = 17.4 KB within ring A region
    u16* kb = (u16*)Cv;
#pragma unroll
    for (int mt = 0; mt < MT; ++mt) {
#pragma unroll
      for (int nt = 0; nt < 4; ++nt) {
#pragma unroll
        for (int r = 0; r < 4; ++r) {
          int lrow = wm + mt * 16 + quad * 4 + r;
          int row = bx * BM + lrow;
          int col = wn + nt * 16 + lcol;
          float v = rstdg[row] * acc[mt][nt][r] - mrstdg[row] * ucol[col] + wcol[col] + bias[col];
          u16 hv = f2b(v);
          if (wn == 0) kb[(size_t)row * 64 + col] = hv;
          else vtile[(col - 64) * 136 + lrow] = hv;
        }
      }
    }
    __syncthreads();
    int dd = t >> 2, js = (t & 3) * 32;
    int bg = bx >> 5, j0g = (bx & 31) * 128;
    u16* dst = VTout + ((size_t)bg * 64 + dd) * 4096 + j0g + js;
#pragma unroll
    for (int i = 0; i < 4; ++i)
      *(uint4*)(dst + i * 8) = *(const uint4*)&vtile[dd * 136 + js + i * 8];
    return;
  }

  u16* Cb = (u16*)Cv;
  float* Cf = (float*)Cv;
  if (SPLITK > 1) Cf += (size_t)bz * (size_t)M * (size_t)N;
#pragma unroll
  for (int mt = 0; mt < MT; ++mt) {
#pragma unroll
    for (int nt = 0; nt < 4; ++nt) {
#pragma unroll
      for (int r = 0; r < 4; ++r) {
        int lrow = wm + mt * 16 + quad * 4 + r;
        int row = bx * BM + lrow;
        int col = by * 128 + wn + nt * 16 + lcol;
        float v = acc[mt][nt][r];
        if (EPI == 1) v += bias[col];
        if (EPI == 3 || EPI == 5)
          v = rstdg[row] * v - mrstdg[row] * ucol[col] + wcol[col] + bias[col];
        if (EPI == 5) v = 0.5f * v * (1.f + erff(v * 0.70710678118f));
        size_t idx = (size_t)row * N + col;
        if (OUTF32) Cf[idx] = v; else Cb[idx] = f2b(v);
      }
    }
  }
}

// ---- wrappers ----
__global__ __launch_bounds__(256) void gemm_wc(const void* Av, const void* Bv, void* Cv) {
  __shared__ __align__(16) u16 lds[16384];
  int vlid = ((int)blockIdx.y) * 1 + (int)blockIdx.x;  // gx=1
  gemm_body<128, 1, 0, 1, 0, false, false>(lds, lds + 8192, Av, Bv, nullptr, nullptr, nullptr,
                                           nullptr, nullptr, nullptr, Cv, nullptr,
                                           128, 1024, 768, 1, 8, 1, vlid);
}
// combined kv (blocks 0..255) + q (blocks 256..447)
__global__ __launch_bounds__(256) void gemm_kvq(
    const void* Akv, const void* Bkv, const float* biaskv, const float* rstdi,
    const float* mrstdi, const float* ui, const float* wi, void* Ckv, u16* VTout,
    const void* Aq, const void* Bq, const float* biasq, const float* rstdq,
    const float* mrstdq, const float* uq, const float* wqv, void* Cq) {
  __shared__ __align__(16) u16 lds[32768];
  int bid = blockIdx.x;
  if (bid < 256) {
    gemm_body<128, 1, 0, 0, 3, false, true>(lds, lds + 16384, Akv, Bkv, biaskv, rstdi, mrstdi,
                                            ui, wi, nullptr, Ckv, VTout,
                                            32768, 128, 1024, 256, 1, 1, bid);
  } else {
    gemm_body<64, 1, 0, 0, 3, false, false>(lds, lds + 8192, Aq, Bq, biasq, rstdq, mrstdq,
                                            uq, wqv, nullptr, Cq, nullptr,
                                            2048, 768, 768, 32, 6, 1, bid - 256);
  }
}
// out-proj with fused 4-way attn merge in A-load
__global__ __launch_bounds__(256) void gemm_o(const void* Av, const void* Bv, const float* bias,
                                              const float* lpart, void* Cv) {
  __shared__ __align__(16) u16 lds[12288];
  int vlid = ((int)blockIdx.y) * 32 + (int)blockIdx.x;
  gemm_body<64, 1, 2, 0, 1, false, false>(lds, lds + 4096, Av, Bv, bias, nullptr, nullptr,
                                          nullptr, nullptr, lpart, Cv, nullptr,
                                          2048, 768, 768, 32, 6, 1, vlid);
}
__global__ __launch_bounds__(256) void gemm_w1(const void* Av, const void* Bv, const float* bias,
                                               const float* rstdg, const float* mrstdg,
                                               const float* ucol, const float* wcol, void* Cv) {
  __shared__ __align__(16) u16 lds[32768];
  int vlid = ((int)blockIdx.y) * 16 + (int)blockIdx.x;
  gemm_body<128, 1, 0, 0, 5, false, false>(lds, lds + 16384, Av, Bv, bias, rstdg, mrstdg,
                                           ucol, wcol, nullptr, Cv, nullptr,
                                           2048, 3072, 768, 16, 24, 1, vlid);
}
__global__ __launch_bounds__(256) void gemm_w2(const void* Av, const void* Bv, void* Cv) {
  __shared__ __align__(16) u16 lds[32768];
  int vlid = (((int)blockIdx.z) * 6 + (int)blockIdx.y) * 16 + (int)blockIdx.x;
  gemm_body<128, 2, 0, 0, 0, true, false>(lds, lds + 16384, Av, Bv, nullptr, nullptr, nullptr,
                                          nullptr, nullptr, nullptr, Cv, nullptr,
                                          2048, 768, 3072, 16, 6, 2, vlid);
}

// ---------------- split-K merge for W2: out = p0 + p1 + h + b2 ----------------
__global__ __launch_bounds__(256) void w2_merge(const float* __restrict__ part,
                                                const float* __restrict__ hf,
                                                const float* __restrict__ b2,
                                                float* __restrict__ out) {
  int idx = blockIdx.x * 256 + threadIdx.x;
  f32x4 p0 = ((const f32x4*)part)[idx];
  f32x4 p1 = ((const f32x4*)part)[idx + 393216];
  f32x4 h = ((const f32x4*)hf)[idx];
  f32x4 bb = ((const f32x4*)b2)[idx % 192];
  f32x4 o;
#pragma unroll
  for (int i = 0; i < 4; ++i) o[i] = p0[i] + p1[i] + h[i] + bb[i];
  ((f32x4*)out)[idx] = o;
}

// ---------------- flash attention, MQA (1 head/block), j-split=4 ----------------
__global__ __launch_bounds__(256) void attn_kernel(const u16* __restrict__ qbuf,
                                                   const u16* __restrict__ kb,
                                                   const u16* __restrict__ VT,
                                                   float* __restrict__ Opart,
                                                   float* __restrict__ lpart) {
  __shared__ __align__(16) u16 k_lds[2][64 * 72];
  __shared__ __align__(16) u16 vt_lds[2][64 * 72];
  __shared__ __align__(16) u16 p_lds[4 * 16 * 72];
  int lid = ((int)blockIdx.z * 12 + (int)blockIdx.y) * 4 + (int)blockIdx.x;
  int wid = (lid & 7) * 192 + (lid >> 3);  // nwg=1536, bijective
  int bi = wid & 3;
  int h = (wid >> 2) % 12;
  int z = wid / 48;
  int b = z >> 2, s = z & 3;
  int t = threadIdx.x;
  int wave = t >> 6, lane = t & 63, quad = lane >> 4, lcol = lane & 15;
  int i0 = bi * 64 + wave * 16;
  const u16* qrow = qbuf + ((size_t)(b * 256 + i0 + lcol) * 768 + h * 64 + quad * 8);
  bf16x8 qf0 = *(const bf16x8*)qrow;
  bf16x8 qf1 = *(const bf16x8*)(qrow + 32);
  float l_r[4] = {0.f, 0.f, 0.f, 0.f};
  f32x4 oacc[4];
#pragma unroll
  for (int nt = 0; nt < 4; ++nt) oacc[nt] = (f32x4){0.f, 0.f, 0.f, 0.f};
  int sr = t >> 2, sc = (t & 3) * 16;
  const u16* kbase = kb + (size_t)b * 4096 * 64;
  const u16* vtbase = VT + (size_t)b * 64 * 4096;
  u16* pw = &p_lds[wave * 16 * 72];

  uint4 kr0, kr1, vr0, vr1;
  auto stage_load = [&](int jt) {
    int j0 = s * 1024 + jt * 64;
    const u16* krow = kbase + (size_t)(j0 + sr) * 64 + sc;
    kr0 = *(const uint4*)(krow);
    kr1 = *(const uint4*)(krow + 8);
    const u16* vrow = vtbase + (size_t)sr * 4096 + j0 + sc;
    vr0 = *(const uint4*)(vrow);
    vr1 = *(const uint4*)(vrow + 8);
  };
  auto stage_store = [&](int buf) {
    *(uint4*)&k_lds[buf][sr * 72 + sc] = kr0;
    *(uint4*)&k_lds[buf][sr * 72 + sc + 8] = kr1;
    *(uint4*)&vt_lds[buf][sr * 72 + sc] = vr0;
    *(uint4*)&vt_lds[buf][sr * 72 + sc + 8] = vr1;
  };

  stage_load(0);
  stage_store(0);
  phase_barrier();
  int cur = 0;
  for (int jt = 0; jt < 16; ++jt) {
    bool more = jt + 1 < 16;
    if (more) stage_load(jt + 1);

    f32x4 sc4[4];
#pragma unroll
    for (int nt = 0; nt < 4; ++nt) sc4[nt] = (f32x4){0.f, 0.f, 0.f, 0.f};
    __builtin_amdgcn_s_setprio(1);
#pragma unroll
    for (int nt = 0; nt < 4; ++nt) {
      bf16x8 kb0 = *(const bf16x8*)&k_lds[cur][(nt * 16 + lcol) * 72 + quad * 8];
      bf16x8 kb1 = *(const bf16x8*)&k_lds[cur][(nt * 16 + lcol) * 72 + 32 + quad * 8];
      sc4[nt] = __builtin_amdgcn_mfma_f32_16x16x32_bf16(qf0, kb0, sc4[nt], 0, 0, 0);
      sc4[nt] = __builtin_amdgcn_mfma_f32_16x16x32_bf16(qf1, kb1, sc4[nt], 0, 0, 0);
    }
    __builtin_amdgcn_s_setprio(0);
#pragma unroll
    for (int r = 0; r < 4; ++r) {
      float rsum = 0.f;
#pragma unroll
      for (int nt = 0; nt < 4; ++nt) {
        float p = __expf(sc4[nt][r] * 0.125f);
        sc4[nt][r] = p;
        rsum += p;
      }
      rsum += __shfl_xor(rsum, 1, 64);
      rsum += __shfl_xor(rsum, 2, 64);
      rsum += __shfl_xor(rsum, 4, 64);
      rsum += __shfl_xor(rsum, 8, 64);
      l_r[r] += rsum;
      uint32_t pk01 = cvt_pk_bf16(sc4[0][r], sc4[1][r]);
      uint32_t pk23 = cvt_pk_bf16(sc4[2][r], sc4[3][r]);
      int prow = (quad * 4 + r) * 72 + lcol;
      pw[prow] = (u16)(pk01 & 0xffff);
      pw[prow + 16] = (u16)(pk01 >> 16);
      pw[prow + 32] = (u16)(pk23 & 0xffff);
      pw[prow + 48] = (u16)(pk23 >> 16);
    }
    __builtin_amdgcn_s_setprio(1);
#pragma unroll
    for (int ks = 0; ks < 2; ++ks) {
      bf16x8 pa = *(const bf16x8*)&pw[lcol * 72 + ks * 32 + quad * 8];
#pragma unroll
      for (int nt = 0; nt < 4; ++nt) {
        bf16x8 vb = *(const bf16x8*)&vt_lds[cur][(nt * 16 + lcol) * 72 + ks * 32 + quad * 8];
        oacc[nt] = __builtin_amdgcn_mfma_f32_16x16x32_bf16(pa, vb, oacc[nt], 0, 0, 0);
      }
    }
    __builtin_amdgcn_s_setprio(0);
    if (more) stage_store(cur ^ 1);
    phase_barrier();
    cur ^= 1;
  }
  size_t base = ((size_t)z * 12 + h) * 256;
#pragma unroll
  for (int r = 0; r < 4; ++r) {
    int row = bi * 64 + wave * 16 + quad * 4 + r;
#pragma unroll
    for (int nt = 0; nt < 4; ++nt)
      Opart[(base + row) * 64 + nt * 16 + lcol] = oacc[nt][r];
    if (lcol == 0) lpart[base + row] = l_r[r];
  }
}

// ---------------- launch ----------------
extern "C" void kernel_launch(void* const* d_in, const int* in_sizes, int n_in, void* d_out,
                              int out_size, void* d_ws, size_t ws_size, hipStream_t stream) {
  (void)in_sizes; (void)n_in; (void)out_size; (void)ws_size;
  const float* hs = (const float*)d_in[0];
  const float* imgf = (const float*)d_in[1];
  const float* ln_img_g = (const float*)d_in[2];
  const float* ln_img_b = (const float*)d_in[3];
  const float* W_bottle = (const float*)d_in[4];
  const float* ln_h_g = (const float*)d_in[5];
  const float* ln_h_b = (const float*)d_in[6];
  const float* Wq = (const float*)d_in[7];
  const float* bq = (const float*)d_in[8];
  const float* Wkv = (const float*)d_in[9];
  const float* bkv = (const float*)d_in[10];
  const float* Wo = (const float*)d_in[11];
  const float* bo = (const float*)d_in[12];
  const float* ln_ao_g = (const float*)d_in[13];
  const float* ln_ao_b = (const float*)d_in[14];
  const float* gatep = (const float*)d_in[15];
  const float* ln_f_g = (const float*)d_in[16];
  const float* ln_f_b = (const float*)d_in[17];
  const float* W1 = (const float*)d_in[18];
  const float* b1 = (const float*)d_in[19];
  const float* W2 = (const float*)d_in[20];
  const float* b2 = (const float*)d_in[21];

  char* sc = (char*)d_ws;
  auto alloc = [&](size_t bytes) {
    char* p = sc;
    sc += (bytes + 63) & ~(size_t)63;
    return p;
  };
  u16* WTq = (u16*)alloc(768 * 768 * 2);
  u16* WTo = (u16*)alloc(768 * 768 * 2);
  u16* WT1 = (u16*)alloc(3072 * 768 * 2);
  u16* WT2 = (u16*)alloc(768 * 3072 * 2);
  u16* WkvT = (u16*)alloc(128 * 768 * 2);
  u16* WcT = (u16*)alloc(128 * 1024 * 2);
  u16* WgT = (u16*)alloc(128 * 1024 * 2);
  u16* WqgT = (u16*)alloc(768 * 768 * 2);
  u16* W1gT = (u16*)alloc(3072 * 768 * 2);
  float* ucol = (float*)alloc(128 * 4);
  float* wcol = (float*)alloc(128 * 4);
  float* uq = (float*)alloc(768 * 4);
  float* wq = (float*)alloc(768 * 4);
  float* u1 = (float*)alloc(3072 * 4);
  float* w1c = (float*)alloc(3072 * 4);
  float* rstdq = (float*)alloc(2048 * 4);
  float* mrstdq = (float*)alloc(2048 * 4);
  float* rstdh = (float*)alloc(2048 * 4);
  float* mrstdh = (float*)alloc(2048 * 4);
  float* rstdi = (float*)alloc(32768 * 4);
  float* mrstdi = (float*)alloc(32768 * 4);
  u16* hs16 = (u16*)alloc(2048 * 768 * 2);
  u16* img16 = (u16*)alloc((size_t)32768 * 1024 * 2);
  u16* kb = (u16*)alloc((size_t)32768 * 64 * 2);
  u16* VT = (u16*)alloc((size_t)8 * 64 * 4096 * 2);
  u16* qb = (u16*)alloc(2048 * 768 * 2);
  u16* ao = (u16*)alloc(2048 * 768 * 2);
  u16* hbuf = (u16*)alloc(2048 * 768 * 2);
  float* hf32 = (float*)alloc(2048 * 768 * 4);
  u16* actb = (u16*)alloc((size_t)2048 * 3072 * 2);
  float* Opart = (float*)alloc((size_t)32 * 12 * 256 * 64 * 4);  // attn partials; reused for W2 split-K
  float* lpart = (float*)alloc((size_t)32 * 12 * 256 * 4);

  // 1. transposes + hs/img rowprep (inputs only — no intra-launch deps)
  prep_main<<<14560, 256, 0, stream>>>(Wq, Wo, W1, W2, Wkv, WTq, WTo, WT1, WT2, WkvT,
                                       hs, hs16, rstdq, mrstdq,
                                       imgf, img16, rstdi, mrstdi);
  // 2. q/w1 LN weight folds (reads WTq/WT1 from launch 1)
  prep_fold<<<960, 256, 0, stream>>>(WTq, ln_h_g, ln_h_b, WqgT, uq, wq,
                                     WT1, ln_f_g, ln_f_b, W1gT, u1, w1c);
  // 3. WcT = WkvT @ W_bottle^T
  gemm_wc<<<dim3(1, 8), 256, 0, stream>>>(WkvT, W_bottle, WcT);
  // 4. img LN weight fold
  prep_wg<<<32, 256, 0, stream>>>(WcT, ln_img_g, ln_img_b, WgT, ucol, wcol, 1024);
  // 5. kv + q co-launched (448 blocks)
  gemm_kvq<<<448, 256, 0, stream>>>(img16, WgT, bkv, rstdi, mrstdi, ucol, wcol, kb, VT,
                                    hs16, WqgT, bq, rstdq, mrstdq, uq, wq, qb);
  // 6. attention (1 head/block, j-split=4)
  attn_kernel<<<dim3(4, 12, 32), 256, 0, stream>>>(qb, kb, VT, Opart, lpart);
  // 7. out proj with fused 4-way merge
  gemm_o<<<dim3(32, 6), 256, 0, stream>>>(Opart, WTo, bo, lpart, ao);
  // 8. h = hs + sigmoid(gate)*LN(ao)
  ln_res<<<512, 256, 0, stream>>>(ao, ln_ao_g, ln_ao_b, hs, gatep, hf32, hbuf, rstdh, mrstdh);
  // 9. act = gelu(LN(h) @ W1 + b1)
  gemm_w1<<<dim3(16, 24), 256, 0, stream>>>(hbuf, W1gT, b1, rstdh, mrstdh, u1, w1c, actb);
  // 10. W2 split-K=2 partials
  gemm_w2<<<dim3(16, 6, 2), 256, 0, stream>>>(actb, WT2, Opart);
  // 11. final merge
  w2_merge<<<1536, 256, 0, stream>>>(Opart, hf32, b2, (float*)d_out);
}

// Round 11
// 494.407 us; speedup vs baseline: 1.0778x; 1.0017x over previous
//
#include <hip/hip_runtime.h>
#include <cstdint>

typedef unsigned short u16;
typedef __bf16 bf16_t;
typedef bf16_t bf16x8 __attribute__((ext_vector_type(8)));
typedef float f32x4 __attribute__((ext_vector_type(4)));

__device__ __forceinline__ float b2f(u16 v) {
  union { uint32_t u; float f; } c; c.u = ((uint32_t)v) << 16; return c.f;
}
__device__ __forceinline__ u16 f2b(float f) {
  union { float f; uint32_t u; } c; c.f = f;
  uint32_t lsb = (c.u >> 16) & 1u;
  return (u16)((c.u + 0x7fffu + lsb) >> 16);
}
__device__ __forceinline__ uint4 pack8(f32x4 a, f32x4 b) {
  union { uint4 v; u16 s[8]; } r;
  r.s[0] = f2b(a[0]); r.s[1] = f2b(a[1]); r.s[2] = f2b(a[2]); r.s[3] = f2b(a[3]);
  r.s[4] = f2b(b[0]); r.s[5] = f2b(b[1]); r.s[6] = f2b(b[2]); r.s[7] = f2b(b[3]);
  return r.v;
}
__device__ __forceinline__ uint32_t cvt_pk_bf16(float lo, float hi) {
  uint32_t r;
  asm("v_cvt_pk_bf16_f32 %0, %1, %2" : "=v"(r) : "v"(lo), "v"(hi));
  return r;
}
__device__ __forceinline__ void phase_barrier() {
  asm volatile("s_waitcnt lgkmcnt(0)" ::: "memory");
  __builtin_amdgcn_s_barrier();
  asm volatile("" ::: "memory");
}
__device__ __forceinline__ void vm_drain() {
  asm volatile("s_waitcnt vmcnt(0)" ::: "memory");
}
template <int N>
__device__ __forceinline__ void vmwait() {
  asm volatile("s_waitcnt vmcnt(%0)" :: "n"(N) : "memory");
}
__device__ __forceinline__ void gload_lds16(const u16* g, u16* l) {
  __builtin_amdgcn_global_load_lds((const __attribute__((address_space(1))) void*)g,
                                   (__attribute__((address_space(3))) void*)l, 16, 0, 0);
}
// bijective chunked XCD swizzle (m204)
__device__ __forceinline__ int xcd_swizzle(int lid, int nwg) {
  int q = nwg >> 3, r = nwg & 7, x = lid & 7, s = lid >> 3;
  return (x < r ? x * (q + 1) : r * (q + 1) + (x - r) * q) + s;
}

// ========== prep_main: 5 transposes + hs rowprep + img rowprep (4 rows/wave ILP) ==========
// All sections read ONLY kernel inputs — no intra-launch dependencies.
__global__ __launch_bounds__(256) void prep_main(
    const float* __restrict__ Wq, const float* __restrict__ Wo, const float* __restrict__ W1,
    const float* __restrict__ W2, const float* __restrict__ Wkv,
    u16* __restrict__ WTq, u16* __restrict__ WTo, u16* __restrict__ WT1,
    u16* __restrict__ WT2, u16* __restrict__ WkvT,
    const float* __restrict__ hs, u16* __restrict__ hs16,
    float* __restrict__ rstdq, float* __restrict__ mrstdq,
    const float* __restrict__ img, u16* __restrict__ img16,
    float* __restrict__ rstdi, float* __restrict__ mrstdi) {
  __shared__ __align__(16) u16 tile[32][33];
  int bid = blockIdx.x;
  int lane = threadIdx.x & 63, w = threadIdx.x >> 6;
  if (bid < 5856) {
    // ---- transposes f32 (R,C) -> bf16 (C,R) ----
    const float* in; u16* out; int R, C, gx, tb;
    if (bid < 576)       { in = Wq;  out = WTq;  R = 768;  C = 768;  gx = 24; tb = bid; }
    else if (bid < 1152) { in = Wo;  out = WTo;  R = 768;  C = 768;  gx = 24; tb = bid - 576; }
    else if (bid < 3456) { in = W1;  out = WT1;  R = 768;  C = 3072; gx = 96; tb = bid - 1152; }
    else if (bid < 5760) { in = W2;  out = WT2;  R = 3072; C = 768;  gx = 24; tb = bid - 3456; }
    else                 { in = Wkv; out = WkvT; R = 768;  C = 128;  gx = 4;  tb = bid - 5760; }
    int c0 = (tb % gx) * 32, r0 = (tb / gx) * 32;
    int tx = threadIdx.x & 31, ty = threadIdx.x >> 5;
#pragma unroll
    for (int i = 0; i < 4; ++i) {
      int r = r0 + ty + i * 8, c = c0 + tx;
      tile[ty + i * 8][tx] = f2b(in[(size_t)r * C + c]);
    }
    __syncthreads();
#pragma unroll
    for (int i = 0; i < 4; ++i) {
      int oc = c0 + ty + i * 8, orr = r0 + tx;
      out[(size_t)oc * R + orr] = tile[tx][ty + i * 8];
    }
  } else if (bid < 6368) {
    // ---- hs f32->bf16 + per-row LN stats ----
    int row = (bid - 5856) * 4 + w;
    const float* x = hs + (size_t)row * 768;
    float v[12];
#pragma unroll
    for (int it = 0; it < 3; ++it) {
      f32x4 d = *(const f32x4*)(x + (lane + it * 64) * 4);
      v[it * 4 + 0] = d[0]; v[it * 4 + 1] = d[1]; v[it * 4 + 2] = d[2]; v[it * 4 + 3] = d[3];
    }
    float s = 0.f, s2 = 0.f;
#pragma unroll
    for (int i = 0; i < 12; ++i) { s += v[i]; s2 += v[i] * v[i]; }
#pragma unroll
    for (int off = 32; off >= 1; off >>= 1) {
      s += __shfl_xor(s, off, 64);
      s2 += __shfl_xor(s2, off, 64);
    }
    float inv_n = 1.0f / 768.f;
    float mean = s * inv_n;
    float var = fmaxf(s2 * inv_n - mean * mean, 0.f);
    float rstd = rsqrtf(var + 1e-5f);
    if (lane == 0) { rstdq[row] = rstd; mrstdq[row] = mean * rstd; }
#pragma unroll
    for (int it = 0; it < 3; ++it) {
      int c = (lane + it * 64) * 4;
      uint2 po;
      po.x = (uint32_t)f2b(v[it * 4 + 0]) | ((uint32_t)f2b(v[it * 4 + 1]) << 16);
      po.y = (uint32_t)f2b(v[it * 4 + 2]) | ((uint32_t)f2b(v[it * 4 + 3]) << 16);
      *(uint2*)(hs16 + (size_t)row * 768 + c) = po;
    }
  } else {
    // ---- img f32->bf16 + per-row LN stats: 4 rows/wave, 16 loads in flight (MLP) ----
    int row0 = (bid - 6368) * 16 + w * 4;
    float v[4][16];
#pragma unroll
    for (int r2 = 0; r2 < 4; ++r2) {
      const float* x = img + (size_t)(row0 + r2) * 1024;
#pragma unroll
      for (int it = 0; it < 4; ++it) {
        f32x4 d = *(const f32x4*)(x + (lane + it * 64) * 4);
        v[r2][it * 4 + 0] = d[0]; v[r2][it * 4 + 1] = d[1];
        v[r2][it * 4 + 2] = d[2]; v[r2][it * 4 + 3] = d[3];
      }
    }
#pragma unroll
    for (int r2 = 0; r2 < 4; ++r2) {
      int row = row0 + r2;
      float s = 0.f, s2 = 0.f;
#pragma unroll
      for (int i = 0; i < 16; ++i) { s += v[r2][i]; s2 += v[r2][i] * v[r2][i]; }
#pragma unroll
      for (int off = 32; off >= 1; off >>= 1) {
        s += __shfl_xor(s, off, 64);
        s2 += __shfl_xor(s2, off, 64);
      }
      float inv_n = 1.0f / 1024.f;
      float mean = s * inv_n;
      float var = fmaxf(s2 * inv_n - mean * mean, 0.f);
      float rstd = rsqrtf(var + 1e-5f);
      if (lane == 0) { rstdi[row] = rstd; mrstdi[row] = mean * rstd; }
#pragma unroll
      for (int it = 0; it < 4; ++it) {
        int c = (lane + it * 64) * 4;
        uint2 po;
        po.x = (uint32_t)f2b(v[r2][it * 4 + 0]) | ((uint32_t)f2b(v[r2][it * 4 + 1]) << 16);
        po.y = (uint32_t)f2b(v[r2][it * 4 + 2]) | ((uint32_t)f2b(v[r2][it * 4 + 3]) << 16);
        *(uint2*)(img16 + (size_t)row * 1024 + c) = po;
      }
    }
  }
}

// ------- img LN weight fold (K=1024, after gemm_wc) -------
__global__ __launch_bounds__(256) void prep_wg(const u16* __restrict__ WT, const float* __restrict__ g,
                                               const float* __restrict__ b, u16* __restrict__ WgT,
                                               float* __restrict__ ucol, float* __restrict__ wcol,
                                               int K) {
  int n = blockIdx.x * 4 + (threadIdx.x >> 6);
  int lane = threadIdx.x & 63;
  const u16* src = WT + (size_t)n * K;
  u16* dst = WgT + (size_t)n * K;
  float su = 0.f, sw = 0.f;
  for (int k = lane; k < K; k += 64) {
    float wc = b2f(src[k]);
    float wg = g[k] * wc;
    dst[k] = f2b(wg);
    su += wg;
    sw += b[k] * wc;
  }
#pragma unroll
  for (int off = 32; off >= 1; off >>= 1) {
    su += __shfl_xor(su, off, 64);
    sw += __shfl_xor(sw, off, 64);
  }
  if (lane == 0) { ucol[n] = su; wcol[n] = sw; }
}

// --- h = hs + sigmoid(gate)*LN(ao): outputs f32 h, bf16 h, per-row LN stats of h ---
__global__ __launch_bounds__(256) void ln_res(const u16* __restrict__ ao, const float* __restrict__ g,
                                              const float* __restrict__ bta,
                                              const float* __restrict__ hs,
                                              const float* __restrict__ gatep,
                                              float* __restrict__ hf, u16* __restrict__ hb,
                                              float* __restrict__ rstdg, float* __restrict__ mrstdg) {
  int row = blockIdx.x * 4 + (threadIdx.x >> 6);
  int lane = threadIdx.x & 63;
  const u16* xb = ao + (size_t)row * 768;
  float v[12];
#pragma unroll
  for (int it = 0; it < 3; ++it) {
    int c = (lane + it * 64) * 4;
    uint2 d = *(const uint2*)(xb + c);
    v[it * 4 + 0] = b2f(d.x & 0xffff); v[it * 4 + 1] = b2f(d.x >> 16);
    v[it * 4 + 2] = b2f(d.y & 0xffff); v[it * 4 + 3] = b2f(d.y >> 16);
  }
  float s = 0.f, s2 = 0.f;
#pragma unroll
  for (int i = 0; i < 12; ++i) { s += v[i]; s2 += v[i] * v[i]; }
#pragma unroll
  for (int off = 32; off >= 1; off >>= 1) {
    s += __shfl_xor(s, off, 64);
    s2 += __shfl_xor(s2, off, 64);
  }
  float inv_n = 1.0f / 768.f;
  float mean = s * inv_n;
  float var = fmaxf(s2 * inv_n - mean * mean, 0.f);
  float rstd = rsqrtf(var + 1e-5f);
  float gate = 1.f / (1.f + __expf(-gatep[0]));
  float hsum = 0.f, hsum2 = 0.f;
  float o[12];
#pragma unroll
  for (int it = 0; it < 3; ++it) {
    int c = (lane + it * 64) * 4;
    const float* rr = hs + (size_t)row * 768 + c;
#pragma unroll
    for (int i = 0; i < 4; ++i) {
      float hv = rr[i] + gate * ((v[it * 4 + i] - mean) * rstd * g[c + i] + bta[c + i]);
      o[it * 4 + i] = hv;
      hsum += hv; hsum2 += hv * hv;
    }
    *(f32x4*)(hf + (size_t)row * 768 + c) = (f32x4){o[it * 4 + 0], o[it * 4 + 1], o[it * 4 + 2], o[it * 4 + 3]};
    uint2 po;
    po.x = (uint32_t)f2b(o[it * 4 + 0]) | ((uint32_t)f2b(o[it * 4 + 1]) << 16);
    po.y = (uint32_t)f2b(o[it * 4 + 2]) | ((uint32_t)f2b(o[it * 4 + 3]) << 16);
    *(uint2*)(hb + (size_t)row * 768 + c) = po;
  }
#pragma unroll
  for (int off = 32; off >= 1; off >>= 1) {
    hsum += __shfl_xor(hsum, off, 64);
    hsum2 += __shfl_xor(hsum2, off, 64);
  }
  float hm = hsum * inv_n;
  float hvar = fmaxf(hsum2 * inv_n - hm * hm, 0.f);
  float hrstd = rsqrtf(hvar + 1e-5f);
  if (lane == 0) { rstdg[row] = hrstd; mrstdg[row] = hm * hrstd; }
}

// ================= MFMA GEMM body: C = A(MxK)*BT(NxK)^T, BMx128 tile, BK=32 =================
// LDS caller-provided; virtual grid allows multiple GEMMs per launch.
// AMODE: 0 bf16-DMA | 2 attn-merge-A (4-way Opart + lpart). BMODE: 0 bf16-DMA | 1 f32-reg.
// PURE(=both DMA): ring-4 + counted vmcnt; else 2-phase.
// EPI: 0 none | 1 +bias | 3 LNfold(precomp)+bias | 5 LNfold+bias+gelu. VTOUT: kv K/V split.
template <int BM, int SPLITK, int AMODE, int BMODE, int EPI, bool OUTF32, bool VTOUT>
__device__ __forceinline__ void gemm_body(u16* __restrict__ aTb, u16* __restrict__ bTb,
                                          const void* __restrict__ Av, const void* __restrict__ Bv,
                                          const float* __restrict__ bias,
                                          const float* __restrict__ rstdg,
                                          const float* __restrict__ mrstdg,
                                          const float* __restrict__ ucol,
                                          const float* __restrict__ wcol,
                                          const float* __restrict__ auxl,
                                          void* __restrict__ Cv, u16* __restrict__ VTout,
                                          int M, int N, int K,
                                          int vgx, int vgy, int vgz, int vlid) {
  constexpr int MT = BM / 32;
  constexpr int AL = BM / 64;
  constexpr bool PURE = (AMODE == 0 && BMODE == 0);
  constexpr int LPT = AL + 2;
  constexpr int ASZ = BM * 32;
  constexpr int BSZ = 128 * 32;

  int nwg = vgx * vgy * vgz;
  int wid = xcd_swizzle(vlid, nwg);
  int bz = wid / (vgx * vgy);
  int rem = wid - bz * (vgx * vgy);
  int bx = rem / vgy;
  int by = rem - bx * vgy;

  int t = threadIdx.x, lane = t & 63, wave = t >> 6;
  int quad = lane >> 4, lcol = lane & 15;
  int wm = (wave >> 1) * (16 * MT), wn = (wave & 1) * 64;
  const u16* Ab = (const u16*)Av;
  const float* Af = (const float*)Av;
  const u16* Bb = (const u16*)Bv;
  const float* Bf = (const float*)Bv;
  const int kchunk = (SPLITK > 1) ? K / SPLITK : K;
  const int kstart = (SPLITK > 1) ? bz * kchunk : 0;
  int rr = t >> 1, rc = t & 1;  // f32 B reg-stage mapping
  f32x4 acc[MT][4];
#pragma unroll
  for (int i = 0; i < MT; ++i)
#pragma unroll
    for (int j = 0; j < 4; ++j) acc[i][j] = (f32x4){0.f, 0.f, 0.f, 0.f};

  f32x4 braw[4];
  f32x4 am0, am1;  // AMODE=2 staging

  auto dmaA = [&](int buf, int k0) {
#pragma unroll
    for (int s2 = 0; s2 < AL; ++s2) {
      int row = (wave * AL + s2) * 16 + (lane >> 2);
      int ch = (lane & 3) ^ (row & 3);
      gload_lds16(Ab + (size_t)(bx * BM + row) * K + kstart + k0 + ch * 8,
                  aTb + buf * ASZ + (wave * AL + s2) * 512);
    }
  };
  auto dmaB = [&](int buf, int k0) {
#pragma unroll
    for (int s2 = 0; s2 < 2; ++s2) {
      int row = (wave * 2 + s2) * 16 + (lane >> 2);
      int ch = (lane & 3) ^ (row & 3);
      gload_lds16(Bb + (size_t)(by * 128 + row) * K + kstart + k0 + ch * 8,
                  bTb + buf * BSZ + (wave * 2 + s2) * 512);
    }
  };
  // AMODE=2 (BM=64): A[row][c] = sum_s Opart / sum_s lpart; 8 cols/thread
  auto loadAmerge = [&](int k0) {
    int c0 = kstart + k0 + (t & 3) * 8;
    int hh = c0 >> 6, dd = c0 & 63;
    int row = bx * 64 + (t >> 2);
    int bb = row >> 8, ii = row & 255;
    am0 = (f32x4){0.f, 0.f, 0.f, 0.f};
    am1 = (f32x4){0.f, 0.f, 0.f, 0.f};
    float lsum = 0.f;
#pragma unroll
    for (int s = 0; s < 4; ++s) {
      size_t base = ((size_t)((bb * 4 + s) * 12 + hh)) * 256 + ii;
      const f32x4* p = (const f32x4*)(Af + base * 64 + dd);
      f32x4 p0 = p[0], p1 = p[1];
#pragma unroll
      for (int j = 0; j < 4; ++j) { am0[j] += p0[j]; am1[j] += p1[j]; }
      lsum += auxl[base];
    }
    float rl = 1.f / lsum;
#pragma unroll
    for (int j = 0; j < 4; ++j) { am0[j] *= rl; am1[j] *= rl; }
  };
  auto storeAmerge = [&](int buf) {
    uint4 c = pack8(am0, am1);
    int ar = t >> 2, ch = t & 3;
    *(uint4*)(aTb + buf * ASZ + ar * 32 + ((ch ^ (ar & 3)) << 3)) = c;
  };
  auto regloadB = [&](int k0) {
    const f32x4* p = (const f32x4*)&Bf[(size_t)(by * 128 + rr) * K + kstart + k0 + rc * 16];
#pragma unroll
    for (int i = 0; i < 4; ++i) braw[i] = p[i];
  };
  auto regstoreB = [&](int buf) {
    uint4 c0 = pack8(braw[0], braw[1]), c1 = pack8(braw[2], braw[3]);
    *(uint4*)(bTb + buf * BSZ + rr * 32 + (((rc * 2 + 0) ^ (rr & 3)) << 3)) = c0;
    *(uint4*)(bTb + buf * BSZ + rr * 32 + (((rc * 2 + 1) ^ (rr & 3)) << 3)) = c1;
  };
  auto compute = [&](int buf) {
    bf16x8 af[MT], bfr[4];
#pragma unroll
    for (int mt = 0; mt < MT; ++mt) {
      int r = wm + mt * 16 + lcol;
      af[mt] = *(const bf16x8*)(aTb + buf * ASZ + r * 32 + (((quad ^ (r & 3))) << 3));
    }
#pragma unroll
    for (int nt = 0; nt < 4; ++nt) {
      int r = wn + nt * 16 + lcol;
      bfr[nt] = *(const bf16x8*)(bTb + buf * BSZ + r * 32 + (((quad ^ (r & 3))) << 3));
    }
#pragma unroll
    for (int mt = 0; mt < MT; ++mt)
#pragma unroll
      for (int nt = 0; nt < 4; ++nt)
        acc[mt][nt] = __builtin_amdgcn_mfma_f32_16x16x32_bf16(af[mt], bfr[nt], acc[mt][nt], 0, 0, 0);
  };

  const int nk = kchunk >> 5;
  if (PURE) {
    // ring-4 + counted vmcnt: 3 tiles in flight, never drain mid-loop
    dmaA(0, 0); dmaB(0, 0);
    if (nk > 1) { dmaA(1, 1 << 5); dmaB(1, 1 << 5); }
    if (nk > 2) { dmaA(2, 2 << 5); dmaB(2, 2 << 5); }
    for (int kt = 0; kt < nk; ++kt) {
      int left = nk - 1 - kt;
      if (left >= 2) vmwait<2 * LPT>();
      else if (left == 1) vmwait<LPT>();
      else vmwait<0>();
      phase_barrier();
      if (kt + 3 < nk) { dmaA((kt + 3) & 3, (kt + 3) << 5); dmaB((kt + 3) & 3, (kt + 3) << 5); }
      compute(kt & 3);
    }
  } else {
    // 2-phase: reg-staged operand(s) + DMA others
    if (AMODE == 2) loadAmerge(0); else dmaA(0, 0);
    if (BMODE == 1) regloadB(0); else dmaB(0, 0);
    if (AMODE == 2) storeAmerge(0);
    if (BMODE == 1) regstoreB(0);
    vm_drain();
    phase_barrier();
    int cur = 0;
    for (int kt = 0; kt < nk; ++kt) {
      bool more = kt + 1 < nk;
      if (more) {
        if (AMODE == 2) loadAmerge((kt + 1) << 5); else dmaA(cur ^ 1, (kt + 1) << 5);
        if (BMODE == 1) regloadB((kt + 1) << 5); else dmaB(cur ^ 1, (kt + 1) << 5);
      }
      compute(cur);
      if (more) {
        if (AMODE == 2) storeAmerge(cur ^ 1);
        if (BMODE == 1) regstoreB(cur ^ 1);
      }
      vm_drain();
      phase_barrier();
      cur ^= 1;
    }
  }

  if (VTOUT) {
    // kv: cols 0..63 -> kb[M][64]; cols 64..127 -> transpose via reused LDS -> VT[b][d][j]
    __syncthreads();
    u16* vtile = aTb;  // 64*136 u16 = 17.4 KB within ring A region
    u16* kb = (u16*)Cv;
#pragma unroll
    for (int mt = 0; mt < MT; ++mt) {
#pragma unroll
      for (int nt = 0; nt < 4; ++nt) {
#pragma unroll
        for (int r = 0; r < 4; ++r) {
          int lrow = wm + mt * 16 + quad * 4 + r;
          int row = bx * BM + lrow;
          int col = wn + nt * 16 + lcol;
          float v = rstdg[row] * acc[mt][nt][r] - mrstdg[row] * ucol[col] + wcol[col] + bias[col];
          u16 hv = f2b(v);
          if (wn == 0) kb[(size_t)row * 64 + col] = hv;
          else vtile[(col - 64) * 136 + lrow] = hv;
        }
      }
    }
    __syncthreads();
    int dd = t >> 2, js = (t & 3) * 32;
    int bg = bx >> 5, j0g = (bx & 31) * 128;
    u16* dst = VTout + ((size_t)bg * 64 + dd) * 4096 + j0g + js;
#pragma unroll
    for (int i = 0; i < 4; ++i)
      *(uint4*)(dst + i * 8) = *(const uint4*)&vtile[dd * 136 + js + i * 8];
    return;
  }

  u16* Cb = (u16*)Cv;
  float* Cf = (float*)Cv;
  if (SPLITK > 1) Cf += (size_t)bz * (size_t)M * (size_t)N;
#pragma unroll
  for (int mt = 0; mt < MT; ++mt) {
#pragma unroll
    for (int nt = 0; nt < 4; ++nt) {
#pragma unroll
      for (int r = 0; r < 4; ++r) {
        int lrow = wm + mt * 16 + quad * 4 + r;
        int row = bx * BM + lrow;
        int col = by * 128 + wn + nt * 16 + lcol;
        float v = acc[mt][nt][r];
        if (EPI == 1) v += bias[col];
        if (EPI == 3 || EPI == 5)
          v = rstdg[row] * v - mrstdg[row] * ucol[col] + wcol[col] + bias[col];
        if (EPI == 5) v = 0.5f * v * (1.f + erff(v * 0.70710678118f));
        size_t idx = (size_t)row * N + col;
        if (OUTF32) Cf[idx] = v; else Cb[idx] = f2b(v);
      }
    }
  }
}

// ---- wrappers ----
// combined prep_fold (blocks 0..959) + gemm_wc (blocks 960..967); both read only
// prep_main outputs + kernel inputs — no intra-launch dependency.
__global__ __launch_bounds__(256) void prep_fold_wc(
    const u16* __restrict__ WTq, const float* __restrict__ gq, const float* __restrict__ bq_,
    u16* __restrict__ WqgT, float* __restrict__ uq, float* __restrict__ wqv,
    const u16* __restrict__ WT1, const float* __restrict__ g1, const float* __restrict__ b1_,
    u16* __restrict__ W1gT, float* __restrict__ u1, float* __restrict__ w1v,
    const void* __restrict__ WkvT, const void* __restrict__ W_bottle, void* __restrict__ WcT) {
  __shared__ __align__(16) u16 lds[16384];
  int bid = blockIdx.x;
  if (bid < 960) {
    int lane = threadIdx.x & 63, w = threadIdx.x >> 6;
    const u16* WT; const float* g; const float* b; u16* WgT; float* u; float* wv; int n0;
    if (bid < 192) { WT = WTq; g = gq; b = bq_; WgT = WqgT; u = uq; wv = wqv; n0 = bid * 4; }
    else { WT = WT1; g = g1; b = b1_; WgT = W1gT; u = u1; wv = w1v; n0 = (bid - 192) * 4; }
    int n = n0 + w;
    const u16* src = WT + (size_t)n * 768;
    u16* dst = WgT + (size_t)n * 768;
    float su = 0.f, sw = 0.f;
    for (int k = lane; k < 768; k += 64) {
      float wc = b2f(src[k]);
      float wg = g[k] * wc;
      dst[k] = f2b(wg);
      su += wg;
      sw += b[k] * wc;
    }
#pragma unroll
    for (int off = 32; off >= 1; off >>= 1) {
      su += __shfl_xor(su, off, 64);
      sw += __shfl_xor(sw, off, 64);
    }
    if (lane == 0) { u[n] = su; wv[n] = sw; }
  } else {
    gemm_body<128, 1, 0, 1, 0, false, false>(lds, lds + 8192, WkvT, W_bottle, nullptr, nullptr,
                                             nullptr, nullptr, nullptr, nullptr, WcT, nullptr,
                                             128, 1024, 768, 1, 8, 1, bid - 960);
  }
}
// combined kv (blocks 0..255) + q (blocks 256..447)
__global__ __launch_bounds__(256) void gemm_kvq(
    const void* Akv, const void* Bkv, const float* biaskv, const float* rstdi,
    const float* mrstdi, const float* ui, const float* wi, void* Ckv, u16* VTout,
    const void* Aq, const void* Bq, const float* biasq, const float* rstdq,
    const float* mrstdq, const float* uq, const float* wqv, void* Cq) {
  __shared__ __align__(16) u16 lds[32768];
  int bid = blockIdx.x;
  if (bid < 256) {
    gemm_body<128, 1, 0, 0, 3, false, true>(lds, lds + 16384, Akv, Bkv, biaskv, rstdi, mrstdi,
                                            ui, wi, nullptr, Ckv, VTout,
                                            32768, 128, 1024, 256, 1, 1, bid);
  } else {
    gemm_body<64, 1, 0, 0, 3, false, false>(lds, lds + 8192, Aq, Bq, biasq, rstdq, mrstdq,
                                            uq, wqv, nullptr, Cq, nullptr,
                                            2048, 768, 768, 32, 6, 1, bid - 256);
  }
}
// out-proj with fused 4-way attn merge in A-load
__global__ __launch_bounds__(256) void gemm_o(const void* Av, const void* Bv, const float* bias,
                                              const float* lpart, void* Cv) {
  __shared__ __align__(16) u16 lds[12288];
  int vlid = ((int)blockIdx.y) * 32 + (int)blockIdx.x;
  gemm_body<64, 1, 2, 0, 1, false, false>(lds, lds + 4096, Av, Bv, bias, nullptr, nullptr,
                                          nullptr, nullptr, lpart, Cv, nullptr,
                                          2048, 768, 768, 32, 6, 1, vlid);
}
__global__ __launch_bounds__(256) void gemm_w1(const void* Av, const void* Bv, const float* bias,
                                               const float* rstdg, const float* mrstdg,
                                               const float* ucol, const float* wcol, void* Cv) {
  __shared__ __align__(16) u16 lds[32768];
  int vlid = ((int)blockIdx.y) * 16 + (int)blockIdx.x;
  gemm_body<128, 1, 0, 0, 5, false, false>(lds, lds + 16384, Av, Bv, bias, rstdg, mrstdg,
                                           ucol, wcol, nullptr, Cv, nullptr,
                                           2048, 3072, 768, 16, 24, 1, vlid);
}
__global__ __launch_bounds__(256) void gemm_w2(const void* Av, const void* Bv, void* Cv) {
  __shared__ __align__(16) u16 lds[32768];
  int vlid = (((int)blockIdx.z) * 6 + (int)blockIdx.y) * 16 + (int)blockIdx.x;
  gemm_body<128, 2, 0, 0, 0, true, false>(lds, lds + 16384, Av, Bv, nullptr, nullptr, nullptr,
                                          nullptr, nullptr, nullptr, Cv, nullptr,
                                          2048, 768, 3072, 16, 6, 2, vlid);
}

// ---------------- split-K merge for W2: out = p0 + p1 + h + b2 ----------------
__global__ __launch_bounds__(256) void w2_merge(const float* __restrict__ part,
                                                const float* __restrict__ hf,
                                                const float* __restrict__ b2,
                                                float* __restrict__ out) {
  int idx = blockIdx.x * 256 + threadIdx.x;
  f32x4 p0 = ((const f32x4*)part)[idx];
  f32x4 p1 = ((const f32x4*)part)[idx + 393216];
  f32x4 h = ((const f32x4*)hf)[idx];
  f32x4 bb = ((const f32x4*)b2)[idx % 192];
  f32x4 o;
#pragma unroll
  for (int i = 0; i < 4; ++i) o[i] = p0[i] + p1[i] + h[i] + bb[i];
  ((f32x4*)out)[idx] = o;
}

// ---------------- flash attention, MQA (1 head/block), j-split=4 ----------------
__global__ __launch_bounds__(256) void attn_kernel(const u16* __restrict__ qbuf,
                                                   const u16* __restrict__ kb,
                                                   const u16* __restrict__ VT,
                                                   float* __restrict__ Opart,
                                                   float* __restrict__ lpart) {
  __shared__ __align__(16) u16 k_lds[2][64 * 72];
  __shared__ __align__(16) u16 vt_lds[2][64 * 72];
  __shared__ __align__(16) u16 p_lds[4 * 16 * 72];
  int lid = ((int)blockIdx.z * 12 + (int)blockIdx.y) * 4 + (int)blockIdx.x;
  int wid = (lid & 7) * 192 + (lid >> 3);  // nwg=1536, bijective
  int bi = wid & 3;
  int h = (wid >> 2) % 12;
  int z = wid / 48;
  int b = z >> 2, s = z & 3;
  int t = threadIdx.x;
  int wave = t >> 6, lane = t & 63, quad = lane >> 4, lcol = lane & 15;
  int i0 = bi * 64 + wave * 16;
  const u16* qrow = qbuf + ((size_t)(b * 256 + i0 + lcol) * 768 + h * 64 + quad * 8);
  bf16x8 qf0 = *(const bf16x8*)qrow;
  bf16x8 qf1 = *(const bf16x8*)(qrow + 32);
  float l_r[4] = {0.f, 0.f, 0.f, 0.f};
  f32x4 oacc[4];
#pragma unroll
  for (int nt = 0; nt < 4; ++nt) oacc[nt] = (f32x4){0.f, 0.f, 0.f, 0.f};
  int sr = t >> 2, sc = (t & 3) * 16;
  const u16* kbase = kb + (size_t)b * 4096 * 64;
  const u16* vtbase = VT + (size_t)b * 64 * 4096;
  u16* pw = &p_lds[wave * 16 * 72];

  uint4 kr0, kr1, vr0, vr1;
  auto stage_load = [&](int jt) {
    int j0 = s * 1024 + jt * 64;
    const u16* krow = kbase + (size_t)(j0 + sr) * 64 + sc;
    kr0 = *(const uint4*)(krow);
    kr1 = *(const uint4*)(krow + 8);
    const u16* vrow = vtbase + (size_t)sr * 4096 + j0 + sc;
    vr0 = *(const uint4*)(vrow);
    vr1 = *(const uint4*)(vrow + 8);
  };
  auto stage_store = [&](int buf) {
    *(uint4*)&k_lds[buf][sr * 72 + sc] = kr0;
    *(uint4*)&k_lds[buf][sr * 72 + sc + 8] = kr1;
    *(uint4*)&vt_lds[buf][sr * 72 + sc] = vr0;
    *(uint4*)&vt_lds[buf][sr * 72 + sc + 8] = vr1;
  };

  stage_load(0);
  stage_store(0);
  phase_barrier();
  int cur = 0;
  for (int jt = 0; jt < 16; ++jt) {
    bool more = jt + 1 < 16;
    if (more) stage_load(jt + 1);

    f32x4 sc4[4];
#pragma unroll
    for (int nt = 0; nt < 4; ++nt) sc4[nt] = (f32x4){0.f, 0.f, 0.f, 0.f};
    __builtin_amdgcn_s_setprio(1);
#pragma unroll
    for (int nt = 0; nt < 4; ++nt) {
      bf16x8 kb0 = *(const bf16x8*)&k_lds[cur][(nt * 16 + lcol) * 72 + quad * 8];
      bf16x8 kb1 = *(const bf16x8*)&k_lds[cur][(nt * 16 + lcol) * 72 + 32 + quad * 8];
      sc4[nt] = __builtin_amdgcn_mfma_f32_16x16x32_bf16(qf0, kb0, sc4[nt], 0, 0, 0);
      sc4[nt] = __builtin_amdgcn_mfma_f32_16x16x32_bf16(qf1, kb1, sc4[nt], 0, 0, 0);
    }
    __builtin_amdgcn_s_setprio(0);
#pragma unroll
    for (int r = 0; r < 4; ++r) {
      float rsum = 0.f;
#pragma unroll
      for (int nt = 0; nt < 4; ++nt) {
        float p = __expf(sc4[nt][r] * 0.125f);
        sc4[nt][r] = p;
        rsum += p;
      }
      rsum += __shfl_xor(rsum, 1, 64);
      rsum += __shfl_xor(rsum, 2, 64);
      rsum += __shfl_xor(rsum, 4, 64);
      rsum += __shfl_xor(rsum, 8, 64);
      l_r[r] += rsum;
      uint32_t pk01 = cvt_pk_bf16(sc4[0][r], sc4[1][r]);
      uint32_t pk23 = cvt_pk_bf16(sc4[2][r], sc4[3][r]);
      int prow = (quad * 4 + r) * 72 + lcol;
      pw[prow] = (u16)(pk01 & 0xffff);
      pw[prow + 16] = (u16)(pk01 >> 16);
      pw[prow + 32] = (u16)(pk23 & 0xffff);
      pw[prow + 48] = (u16)(pk23 >> 16);
    }
    __builtin_amdgcn_s_setprio(1);
#pragma unroll
    for (int ks = 0; ks < 2; ++ks) {
      bf16x8 pa = *(const bf16x8*)&pw[lcol * 72 + ks * 32 + quad * 8];
#pragma unroll
      for (int nt = 0; nt < 4; ++nt) {
        bf16x8 vb = *(const bf16x8*)&vt_lds[cur][(nt * 16 + lcol) * 72 + ks * 32 + quad * 8];
        oacc[nt] = __builtin_amdgcn_mfma_f32_16x16x32_bf16(pa, vb, oacc[nt], 0, 0, 0);
      }
    }
    __builtin_amdgcn_s_setprio(0);
    if (more) stage_store(cur ^ 1);
    phase_barrier();
    cur ^= 1;
  }
  size_t base = ((size_t)z * 12 + h) * 256;
#pragma unroll
  for (int r = 0; r < 4; ++r) {
    int row = bi * 64 + wave * 16 + quad * 4 + r;
#pragma unroll
    for (int nt = 0; nt < 4; ++nt)
      Opart[(base + row) * 64 + nt * 16 + lcol] = oacc[nt][r];
    if (lcol == 0) lpart[base + row] = l_r[r];
  }
}

// ---------------- launch ----------------
extern "C" void kernel_launch(void* const* d_in, const int* in_sizes, int n_in, void* d_out,
                              int out_size, void* d_ws, size_t ws_size, hipStream_t stream) {
  (void)in_sizes; (void)n_in; (void)out_size; (void)ws_size;
  const float* hs = (const float*)d_in[0];
  const float* imgf = (const float*)d_in[1];
  const float* ln_img_g = (const float*)d_in[2];
  const float* ln_img_b = (const float*)d_in[3];
  const float* W_bottle = (const float*)d_in[4];
  const float* ln_h_g = (const float*)d_in[5];
  const float* ln_h_b = (const float*)d_in[6];
  const float* Wq = (const float*)d_in[7];
  const float* bq = (const float*)d_in[8];
  const float* Wkv = (const float*)d_in[9];
  const float* bkv = (const float*)d_in[10];
  const float* Wo = (const float*)d_in[11];
  const float* bo = (const float*)d_in[12];
  const float* ln_ao_g = (const float*)d_in[13];
  const float* ln_ao_b = (const float*)d_in[14];
  const float* gatep = (const float*)d_in[15];
  const float* ln_f_g = (const float*)d_in[16];
  const float* ln_f_b = (const float*)d_in[17];
  const float* W1 = (const float*)d_in[18];
  const float* b1 = (const float*)d_in[19];
  const float* W2 = (const float*)d_in[20];
  const float* b2 = (const float*)d_in[21];

  char* sc = (char*)d_ws;
  auto alloc = [&](size_t bytes) {
    char* p = sc;
    sc += (bytes + 63) & ~(size_t)63;
    return p;
  };
  u16* WTq = (u16*)alloc(768 * 768 * 2);
  u16* WTo = (u16*)alloc(768 * 768 * 2);
  u16* WT1 = (u16*)alloc(3072 * 768 * 2);
  u16* WT2 = (u16*)alloc(768 * 3072 * 2);
  u16* WkvT = (u16*)alloc(128 * 768 * 2);
  u16* WcT = (u16*)alloc(128 * 1024 * 2);
  u16* WgT = (u16*)alloc(128 * 1024 * 2);
  u16* WqgT = (u16*)alloc(768 * 768 * 2);
  u16* W1gT = (u16*)alloc(3072 * 768 * 2);
  float* ucol = (float*)alloc(128 * 4);
  float* wcol = (float*)alloc(128 * 4);
  float* uq = (float*)alloc(768 * 4);
  float* wq = (float*)alloc(768 * 4);
  float* u1 = (float*)alloc(3072 * 4);
  float* w1c = (float*)alloc(3072 * 4);
  float* rstdq = (float*)alloc(2048 * 4);
  float* mrstdq = (float*)alloc(2048 * 4);
  float* rstdh = (float*)alloc(2048 * 4);
  float* mrstdh = (float*)alloc(2048 * 4);
  float* rstdi = (float*)alloc(32768 * 4);
  float* mrstdi = (float*)alloc(32768 * 4);
  u16* hs16 = (u16*)alloc(2048 * 768 * 2);
  u16* img16 = (u16*)alloc((size_t)32768 * 1024 * 2);
  u16* kb = (u16*)alloc((size_t)32768 * 64 * 2);
  u16* VT = (u16*)alloc((size_t)8 * 64 * 4096 * 2);
  u16* qb = (u16*)alloc(2048 * 768 * 2);
  u16* ao = (u16*)alloc(2048 * 768 * 2);
  u16* hbuf = (u16*)alloc(2048 * 768 * 2);
  float* hf32 = (float*)alloc(2048 * 768 * 4);
  u16* actb = (u16*)alloc((size_t)2048 * 3072 * 2);
  float* Opart = (float*)alloc((size_t)32 * 12 * 256 * 64 * 4);  // attn partials; reused for W2 split-K
  float* lpart = (float*)alloc((size_t)32 * 12 * 256 * 4);

  // 1. transposes + hs rowprep + img rowprep (4 rows/wave ILP)
  prep_main<<<8416, 256, 0, stream>>>(Wq, Wo, W1, W2, Wkv, WTq, WTo, WT1, WT2, WkvT,
                                      hs, hs16, rstdq, mrstdq,
                                      imgf, img16, rstdi, mrstdi);
  // 2. q/w1 LN weight folds + WcT GEMM (co-launched; both read launch-1 outputs only)
  prep_fold_wc<<<968, 256, 0, stream>>>(WTq, ln_h_g, ln_h_b, WqgT, uq, wq,
                                        WT1, ln_f_g, ln_f_b, W1gT, u1, w1c,
                                        WkvT, W_bottle, WcT);
  // 3. img LN weight fold
  prep_wg<<<32, 256, 0, stream>>>(WcT, ln_img_g, ln_img_b, WgT, ucol, wcol, 1024);
  // 4. kv + q co-launched (448 blocks)
  gemm_kvq<<<448, 256, 0, stream>>>(img16, WgT, bkv, rstdi, mrstdi, ucol, wcol, kb, VT,
                                    hs16, WqgT, bq, rstdq, mrstdq, uq, wq, qb);
  // 5. attention (1 head/block, j-split=4)
  attn_kernel<<<dim3(4, 12, 32), 256, 0, stream>>>(qb, kb, VT, Opart, lpart);
  // 6. out proj with fused 4-way merge
  gemm_o<<<dim3(32, 6), 256, 0, stream>>>(Opart, WTo, bo, lpart, ao);
  // 7. h = hs + sigmoid(gate)*LN(ao)
  ln_res<<<512, 256, 0, stream>>>(ao, ln_ao_g, ln_ao_b, hs, gatep, hf32, hbuf, rstdh, mrstdh);
  // 8. act = gelu(LN(h) @ W1 + b1)
  gemm_w1<<<dim3(16, 24), 256, 0, stream>>>(hbuf, W1gT, b1, rstdh, mrstdh, u1, w1c, actb);
  // 9. W2 split-K=2 partials
  gemm_w2<<<dim3(16, 6, 2), 256, 0, stream>>>(actb, WT2, Opart);
  // 10. final merge
  w2_merge<<<1536, 256, 0, stream>>>(Opart, hf32, b2, (float*)d_out);
}

// Round 12
// 483.034 us; speedup vs baseline: 1.1032x; 1.0235x over previous
//
#include <hip/hip_runtime.h>
#include <cstdint>

typedef unsigned short u16;
typedef __bf16 bf16_t;
typedef bf16_t bf16x8 __attribute__((ext_vector_type(8)));
typedef float f32x4 __attribute__((ext_vector_type(4)));

__device__ __forceinline__ float b2f(u16 v) {
  union { uint32_t u; float f; } c; c.u = ((uint32_t)v) << 16; return c.f;
}
__device__ __forceinline__ u16 f2b(float f) {
  union { float f; uint32_t u; } c; c.f = f;
  uint32_t lsb = (c.u >> 16) & 1u;
  return (u16)((c.u + 0x7fffu + lsb) >> 16);
}
__device__ __forceinline__ uint4 pack8(f32x4 a, f32x4 b) {
  union { uint4 v; u16 s[8]; } r;
  r.s[0] = f2b(a[0]); r.s[1] = f2b(a[1]); r.s[2] = f2b(a[2]); r.s[3] = f2b(a[3]);
  r.s[4] = f2b(b[0]); r.s[5] = f2b(b[1]); r.s[6] = f2b(b[2]); r.s[7] = f2b(b[3]);
  return r.v;
}
__device__ __forceinline__ uint32_t cvt_pk_bf16(float lo, float hi) {
  uint32_t r;
  asm("v_cvt_pk_bf16_f32 %0, %1, %2" : "=v"(r) : "v"(lo), "v"(hi));
  return r;
}
__device__ __forceinline__ void phase_barrier() {
  asm volatile("s_waitcnt lgkmcnt(0)" ::: "memory");
  __builtin_amdgcn_s_barrier();
  asm volatile("" ::: "memory");
}
__device__ __forceinline__ void vm_drain() {
  asm volatile("s_waitcnt vmcnt(0)" ::: "memory");
}
template <int N>
__device__ __forceinline__ void vmwait() {
  asm volatile("s_waitcnt vmcnt(%0)" :: "n"(N) : "memory");
}
__device__ __forceinline__ void gload_lds16(const u16* g, u16* l) {
  __builtin_amdgcn_global_load_lds((const __attribute__((address_space(1))) void*)g,
                                   (__attribute__((address_space(3))) void*)l, 16, 0, 0);
}
// bijective chunked XCD swizzle (m204)
__device__ __forceinline__ int xcd_swizzle(int lid, int nwg) {
  int q = nwg >> 3, r = nwg & 7, x = lid & 7, s = lid >> 3;
  return (x < r ? x * (q + 1) : r * (q + 1) + (x - r) * q) + s;
}

// ========== prep_main: 5 transposes + hs rowprep (reads ONLY kernel inputs) ==========
__global__ __launch_bounds__(256) void prep_main(
    const float* __restrict__ Wq, const float* __restrict__ Wo, const float* __restrict__ W1,
    const float* __restrict__ W2, const float* __restrict__ Wkv,
    u16* __restrict__ WTq, u16* __restrict__ WTo, u16* __restrict__ WT1,
    u16* __restrict__ WT2, u16* __restrict__ WkvT,
    const float* __restrict__ hs, u16* __restrict__ hs16,
    float* __restrict__ rstdq, float* __restrict__ mrstdq) {
  __shared__ __align__(16) u16 tile[32][33];
  int bid = blockIdx.x;
  int lane = threadIdx.x & 63, w = threadIdx.x >> 6;
  if (bid < 5856) {
    // ---- transposes f32 (R,C) -> bf16 (C,R) ----
    const float* in; u16* out; int R, C, gx, tb;
    if (bid < 576)       { in = Wq;  out = WTq;  R = 768;  C = 768;  gx = 24; tb = bid; }
    else if (bid < 1152) { in = Wo;  out = WTo;  R = 768;  C = 768;  gx = 24; tb = bid - 576; }
    else if (bid < 3456) { in = W1;  out = WT1;  R = 768;  C = 3072; gx = 96; tb = bid - 1152; }
    else if (bid < 5760) { in = W2;  out = WT2;  R = 3072; C = 768;  gx = 24; tb = bid - 3456; }
    else                 { in = Wkv; out = WkvT; R = 768;  C = 128;  gx = 4;  tb = bid - 5760; }
    int c0 = (tb % gx) * 32, r0 = (tb / gx) * 32;
    int tx = threadIdx.x & 31, ty = threadIdx.x >> 5;
#pragma unroll
    for (int i = 0; i < 4; ++i) {
      int r = r0 + ty + i * 8, c = c0 + tx;
      tile[ty + i * 8][tx] = f2b(in[(size_t)r * C + c]);
    }
    __syncthreads();
#pragma unroll
    for (int i = 0; i < 4; ++i) {
      int oc = c0 + ty + i * 8, orr = r0 + tx;
      out[(size_t)oc * R + orr] = tile[tx][ty + i * 8];
    }
  } else {
    // ---- hs f32->bf16 + per-row LN stats ----
    int row = (bid - 5856) * 4 + w;
    const float* x = hs + (size_t)row * 768;
    float v[12];
#pragma unroll
    for (int it = 0; it < 3; ++it) {
      f32x4 d = *(const f32x4*)(x + (lane + it * 64) * 4);
      v[it * 4 + 0] = d[0]; v[it * 4 + 1] = d[1]; v[it * 4 + 2] = d[2]; v[it * 4 + 3] = d[3];
    }
    float s = 0.f, s2 = 0.f;
#pragma unroll
    for (int i = 0; i < 12; ++i) { s += v[i]; s2 += v[i] * v[i]; }
#pragma unroll
    for (int off = 32; off >= 1; off >>= 1) {
      s += __shfl_xor(s, off, 64);
      s2 += __shfl_xor(s2, off, 64);
    }
    float inv_n = 1.0f / 768.f;
    float mean = s * inv_n;
    float var = fmaxf(s2 * inv_n - mean * mean, 0.f);
    float rstd = rsqrtf(var + 1e-5f);
    if (lane == 0) { rstdq[row] = rstd; mrstdq[row] = mean * rstd; }
#pragma unroll
    for (int it = 0; it < 3; ++it) {
      int c = (lane + it * 64) * 4;
      uint2 po;
      po.x = (uint32_t)f2b(v[it * 4 + 0]) | ((uint32_t)f2b(v[it * 4 + 1]) << 16);
      po.y = (uint32_t)f2b(v[it * 4 + 2]) | ((uint32_t)f2b(v[it * 4 + 3]) << 16);
      *(uint2*)(hs16 + (size_t)row * 768 + c) = po;
    }
  }
}

// ------- img LN weight fold (K=1024, after gemm_wc) -------
__global__ __launch_bounds__(256) void prep_wg(const u16* __restrict__ WT, const float* __restrict__ g,
                                               const float* __restrict__ b, u16* __restrict__ WgT,
                                               float* __restrict__ ucol, float* __restrict__ wcol,
                                               int K) {
  int n = blockIdx.x * 4 + (threadIdx.x >> 6);
  int lane = threadIdx.x & 63;
  const u16* src = WT + (size_t)n * K;
  u16* dst = WgT + (size_t)n * K;
  float su = 0.f, sw = 0.f;
  for (int k = lane; k < K; k += 64) {
    float wc = b2f(src[k]);
    float wg = g[k] * wc;
    dst[k] = f2b(wg);
    su += wg;
    sw += b[k] * wc;
  }
#pragma unroll
  for (int off = 32; off >= 1; off >>= 1) {
    su += __shfl_xor(su, off, 64);
    sw += __shfl_xor(sw, off, 64);
  }
  if (lane == 0) { ucol[n] = su; wcol[n] = sw; }
}

// --- h = hs + sigmoid(gate)*LN(ao): outputs f32 h, bf16 h, per-row LN stats of h ---
__global__ __launch_bounds__(256) void ln_res(const u16* __restrict__ ao, const float* __restrict__ g,
                                              const float* __restrict__ bta,
                                              const float* __restrict__ hs,
                                              const float* __restrict__ gatep,
                                              float* __restrict__ hf, u16* __restrict__ hb,
                                              float* __restrict__ rstdg, float* __restrict__ mrstdg) {
  int row = blockIdx.x * 4 + (threadIdx.x >> 6);
  int lane = threadIdx.x & 63;
  const u16* xb = ao + (size_t)row * 768;
  float v[12];
#pragma unroll
  for (int it = 0; it < 3; ++it) {
    int c = (lane + it * 64) * 4;
    uint2 d = *(const uint2*)(xb + c);
    v[it * 4 + 0] = b2f(d.x & 0xffff); v[it * 4 + 1] = b2f(d.x >> 16);
    v[it * 4 + 2] = b2f(d.y & 0xffff); v[it * 4 + 3] = b2f(d.y >> 16);
  }
  float s = 0.f, s2 = 0.f;
#pragma unroll
  for (int i = 0; i < 12; ++i) { s += v[i]; s2 += v[i] * v[i]; }
#pragma unroll
  for (int off = 32; off >= 1; off >>= 1) {
    s += __shfl_xor(s, off, 64);
    s2 += __shfl_xor(s2, off, 64);
  }
  float inv_n = 1.0f / 768.f;
  float mean = s * inv_n;
  float var = fmaxf(s2 * inv_n - mean * mean, 0.f);
  float rstd = rsqrtf(var + 1e-5f);
  float gate = 1.f / (1.f + __expf(-gatep[0]));
  float hsum = 0.f, hsum2 = 0.f;
  float o[12];
#pragma unroll
  for (int it = 0; it < 3; ++it) {
    int c = (lane + it * 64) * 4;
    const float* rr = hs + (size_t)row * 768 + c;
#pragma unroll
    for (int i = 0; i < 4; ++i) {
      float hv = rr[i] + gate * ((v[it * 4 + i] - mean) * rstd * g[c + i] + bta[c + i]);
      o[it * 4 + i] = hv;
      hsum += hv; hsum2 += hv * hv;
    }
    *(f32x4*)(hf + (size_t)row * 768 + c) = (f32x4){o[it * 4 + 0], o[it * 4 + 1], o[it * 4 + 2], o[it * 4 + 3]};
    uint2 po;
    po.x = (uint32_t)f2b(o[it * 4 + 0]) | ((uint32_t)f2b(o[it * 4 + 1]) << 16);
    po.y = (uint32_t)f2b(o[it * 4 + 2]) | ((uint32_t)f2b(o[it * 4 + 3]) << 16);
    *(uint2*)(hb + (size_t)row * 768 + c) = po;
  }
#pragma unroll
  for (int off = 32; off >= 1; off >>= 1) {
    hsum += __shfl_xor(hsum, off, 64);
    hsum2 += __shfl_xor(hsum2, off, 64);
  }
  float hm = hsum * inv_n;
  float hvar = fmaxf(hsum2 * inv_n - hm * hm, 0.f);
  float hrstd = rsqrtf(hvar + 1e-5f);
  if (lane == 0) { rstdg[row] = hrstd; mrstdg[row] = hm * hrstd; }
}

// ================= MFMA GEMM body: C = A(MxK)*BT(NxK)^T, BMx128 tile, BK=32 =================
// LDS caller-provided; virtual grid allows multiple GEMMs per launch.
// AMODE: 0 bf16-DMA | 1 f32-reg (pack at store; EPI=4 accumulates LN stats) |
//        2 attn-merge-A (4-way Opart + lpart).
// BMODE: 0 bf16-DMA | 1 f32-reg. PURE(=both DMA): ring-4 + counted vmcnt; else 2-phase.
// EPI: 0 none | 1 +bias | 3 LNfold(precomp)+bias | 4 LNfold(in-GEMM stats)+bias |
//      5 LNfold(precomp)+bias+gelu. VTOUT: kv K/V split epilogue.
template <int BM, int SPLITK, int AMODE, int BMODE, int EPI, bool OUTF32, bool VTOUT>
__device__ __forceinline__ void gemm_body(u16* __restrict__ aTb, u16* __restrict__ bTb,
                                          const void* __restrict__ Av, const void* __restrict__ Bv,
                                          const float* __restrict__ bias,
                                          const float* __restrict__ rstdg,
                                          const float* __restrict__ mrstdg,
                                          const float* __restrict__ ucol,
                                          const float* __restrict__ wcol,
                                          const float* __restrict__ auxl,
                                          void* __restrict__ Cv, u16* __restrict__ VTout,
                                          int M, int N, int K,
                                          int vgx, int vgy, int vgz, int vlid) {
  constexpr int MT = BM / 32;
  constexpr int AL = BM / 64;
  constexpr bool PURE = (AMODE == 0 && BMODE == 0);
  constexpr int LPT = AL + 2;
  constexpr int ASZ = BM * 32;
  constexpr int BSZ = 128 * 32;
  __shared__ float rstd_s[EPI == 4 ? 128 : 1];
  __shared__ float mrstd_s[EPI == 4 ? 128 : 1];

  int nwg = vgx * vgy * vgz;
  int wid = xcd_swizzle(vlid, nwg);
  int bz = wid / (vgx * vgy);
  int rem = wid - bz * (vgx * vgy);
  int bx = rem / vgy;
  int by = rem - bx * vgy;

  int t = threadIdx.x, lane = t & 63, wave = t >> 6;
  int quad = lane >> 4, lcol = lane & 15;
  int wm = (wave >> 1) * (16 * MT), wn = (wave & 1) * 64;
  const u16* Ab = (const u16*)Av;
  const float* Af = (const float*)Av;
  const u16* Bb = (const u16*)Bv;
  const float* Bf = (const float*)Bv;
  const int kchunk = (SPLITK > 1) ? K / SPLITK : K;
  const int kstart = (SPLITK > 1) ? bz * kchunk : 0;
  int rr = t >> 1, rc = t & 1;  // f32 reg-stage mapping (A and B)
  float sa = 0.f, sa2 = 0.f;
  f32x4 acc[MT][4];
#pragma unroll
  for (int i = 0; i < MT; ++i)
#pragma unroll
    for (int j = 0; j < 4; ++j) acc[i][j] = (f32x4){0.f, 0.f, 0.f, 0.f};

  f32x4 araw[4], braw[4];
  f32x4 am0, am1;  // AMODE=2 staging

  auto dmaA = [&](int buf, int k0) {
#pragma unroll
    for (int s2 = 0; s2 < AL; ++s2) {
      int row = (wave * AL + s2) * 16 + (lane >> 2);
      int ch = (lane & 3) ^ (row & 3);
      gload_lds16(Ab + (size_t)(bx * BM + row) * K + kstart + k0 + ch * 8,
                  aTb + buf * ASZ + (wave * AL + s2) * 512);
    }
  };
  auto dmaB = [&](int buf, int k0) {
#pragma unroll
    for (int s2 = 0; s2 < 2; ++s2) {
      int row = (wave * 2 + s2) * 16 + (lane >> 2);
      int ch = (lane & 3) ^ (row & 3);
      gload_lds16(Bb + (size_t)(by * 128 + row) * K + kstart + k0 + ch * 8,
                  bTb + buf * BSZ + (wave * 2 + s2) * 512);
    }
  };
  // AMODE=1 (BM=128): f32 A reg-staged; pack + optional LN stats at store site
  auto regloadA = [&](int k0) {
    const f32x4* p = (const f32x4*)&Af[(size_t)(bx * BM + rr) * K + kstart + k0 + rc * 16];
#pragma unroll
    for (int i = 0; i < 4; ++i) araw[i] = p[i];
  };
  auto regstoreA = [&](int buf) {
    if (EPI == 4) {
#pragma unroll
      for (int i = 0; i < 4; ++i)
#pragma unroll
        for (int j = 0; j < 4; ++j) { sa += araw[i][j]; sa2 += araw[i][j] * araw[i][j]; }
    }
    uint4 c0 = pack8(araw[0], araw[1]), c1 = pack8(araw[2], araw[3]);
    *(uint4*)(aTb + buf * ASZ + rr * 32 + (((rc * 2 + 0) ^ (rr & 3)) << 3)) = c0;
    *(uint4*)(aTb + buf * ASZ + rr * 32 + (((rc * 2 + 1) ^ (rr & 3)) << 3)) = c1;
  };
  // AMODE=2 (BM=64): A[row][c] = sum_s Opart / sum_s lpart; 8 cols/thread
  auto loadAmerge = [&](int k0) {
    int c0 = kstart + k0 + (t & 3) * 8;
    int hh = c0 >> 6, dd = c0 & 63;
    int row = bx * 64 + (t >> 2);
    int bb = row >> 8, ii = row & 255;
    am0 = (f32x4){0.f, 0.f, 0.f, 0.f};
    am1 = (f32x4){0.f, 0.f, 0.f, 0.f};
    float lsum = 0.f;
#pragma unroll
    for (int s = 0; s < 4; ++s) {
      size_t base = ((size_t)((bb * 4 + s) * 12 + hh)) * 256 + ii;
      const f32x4* p = (const f32x4*)(Af + base * 64 + dd);
      f32x4 p0 = p[0], p1 = p[1];
#pragma unroll
      for (int j = 0; j < 4; ++j) { am0[j] += p0[j]; am1[j] += p1[j]; }
      lsum += auxl[base];
    }
    float rl = 1.f / lsum;
#pragma unroll
    for (int j = 0; j < 4; ++j) { am0[j] *= rl; am1[j] *= rl; }
  };
  auto storeAmerge = [&](int buf) {
    uint4 c = pack8(am0, am1);
    int ar = t >> 2, ch = t & 3;
    *(uint4*)(aTb + buf * ASZ + ar * 32 + ((ch ^ (ar & 3)) << 3)) = c;
  };
  auto regloadB = [&](int k0) {
    const f32x4* p = (const f32x4*)&Bf[(size_t)(by * 128 + rr) * K + kstart + k0 + rc * 16];
#pragma unroll
    for (int i = 0; i < 4; ++i) braw[i] = p[i];
  };
  auto regstoreB = [&](int buf) {
    uint4 c0 = pack8(braw[0], braw[1]), c1 = pack8(braw[2], braw[3]);
    *(uint4*)(bTb + buf * BSZ + rr * 32 + (((rc * 2 + 0) ^ (rr & 3)) << 3)) = c0;
    *(uint4*)(bTb + buf * BSZ + rr * 32 + (((rc * 2 + 1) ^ (rr & 3)) << 3)) = c1;
  };
  auto compute = [&](int buf) {
    bf16x8 af[MT], bfr[4];
#pragma unroll
    for (int mt = 0; mt < MT; ++mt) {
      int r = wm + mt * 16 + lcol;
      af[mt] = *(const bf16x8*)(aTb + buf * ASZ + r * 32 + (((quad ^ (r & 3))) << 3));
    }
#pragma unroll
    for (int nt = 0; nt < 4; ++nt) {
      int r = wn + nt * 16 + lcol;
      bfr[nt] = *(const bf16x8*)(bTb + buf * BSZ + r * 32 + (((quad ^ (r & 3))) << 3));
    }
#pragma unroll
    for (int mt = 0; mt < MT; ++mt)
#pragma unroll
      for (int nt = 0; nt < 4; ++nt)
        acc[mt][nt] = __builtin_amdgcn_mfma_f32_16x16x32_bf16(af[mt], bfr[nt], acc[mt][nt], 0, 0, 0);
  };

  const int nk = kchunk >> 5;
  if (PURE) {
    // ring-4 + counted vmcnt: 3 tiles in flight, never drain mid-loop
    dmaA(0, 0); dmaB(0, 0);
    if (nk > 1) { dmaA(1, 1 << 5); dmaB(1, 1 << 5); }
    if (nk > 2) { dmaA(2, 2 << 5); dmaB(2, 2 << 5); }
    for (int kt = 0; kt < nk; ++kt) {
      int left = nk - 1 - kt;
      if (left >= 2) vmwait<2 * LPT>();
      else if (left == 1) vmwait<LPT>();
      else vmwait<0>();
      phase_barrier();
      if (kt + 3 < nk) { dmaA((kt + 3) & 3, (kt + 3) << 5); dmaB((kt + 3) & 3, (kt + 3) << 5); }
      compute(kt & 3);
    }
  } else {
    // 2-phase: reg-staged operand(s) + DMA others
    if (AMODE == 1) regloadA(0); else if (AMODE == 2) loadAmerge(0); else dmaA(0, 0);
    if (BMODE == 1) regloadB(0); else dmaB(0, 0);
    if (AMODE == 1) regstoreA(0);
    if (AMODE == 2) storeAmerge(0);
    if (BMODE == 1) regstoreB(0);
    vm_drain();
    phase_barrier();
    int cur = 0;
    for (int kt = 0; kt < nk; ++kt) {
      bool more = kt + 1 < nk;
      if (more) {
        if (AMODE == 1) regloadA((kt + 1) << 5);
        else if (AMODE == 2) loadAmerge((kt + 1) << 5);
        else dmaA(cur ^ 1, (kt + 1) << 5);
        if (BMODE == 1) regloadB((kt + 1) << 5); else dmaB(cur ^ 1, (kt + 1) << 5);
      }
      compute(cur);
      if (more) {
        if (AMODE == 1) regstoreA(cur ^ 1);
        if (AMODE == 2) storeAmerge(cur ^ 1);
        if (BMODE == 1) regstoreB(cur ^ 1);
      }
      vm_drain();
      phase_barrier();
      cur ^= 1;
    }
  }

  if (EPI == 4) {
    // in-GEMM LN row stats: 2 threads per row (rr), partner via lane^1
    float s = sa, s2 = sa2;
    s += __shfl_xor(s, 1, 64);
    s2 += __shfl_xor(s2, 1, 64);
    if ((t & 1) == 0) {
      float inv_n = 1.0f / (float)K;
      float mean = s * inv_n;
      float var = fmaxf(s2 * inv_n - mean * mean, 0.f);
      float rstd = rsqrtf(var + 1e-5f);
      rstd_s[rr] = rstd;
      mrstd_s[rr] = mean * rstd;
    }
    __syncthreads();
  }

  if (VTOUT) {
    // kv: cols 0..63 -> kb[M][64]; cols 64..127 -> transpose via reused LDS -> VT[b][d][j]
    __syncthreads();
    u16* vtile = aTb;  // 64*136 u16 = 17.4 KB (A region + spill into dead B region)
    u16* kb = (u16*)Cv;
#pragma unroll
    for (int mt = 0; mt < MT; ++mt) {
#pragma unroll
      for (int nt = 0; nt < 4; ++nt) {
#pragma unroll
        for (int r = 0; r < 4; ++r) {
          int lrow = wm + mt * 16 + quad * 4 + r;
          int row = bx * BM + lrow;
          int col = wn + nt * 16 + lcol;
          float R = (EPI == 4) ? rstd_s[lrow] : rstdg[row];
          float MR = (EPI == 4) ? mrstd_s[lrow] : mrstdg[row];
          float v = R * acc[mt][nt][r] - MR * ucol[col] + wcol[col] + bias[col];
          u16 hv = f2b(v);
          if (wn == 0) kb[(size_t)row * 64 + col] = hv;
          else vtile[(col - 64) * 136 + lrow] = hv;
        }
      }
    }
    __syncthreads();
    int dd = t >> 2, js = (t & 3) * 32;
    int bg = bx >> 5, j0g = (bx & 31) * 128;
    u16* dst = VTout + ((size_t)bg * 64 + dd) * 4096 + j0g + js;
#pragma unroll
    for (int i = 0; i < 4; ++i)
      *(uint4*)(dst + i * 8) = *(const uint4*)&vtile[dd * 136 + js + i * 8];
    return;
  }

  u16* Cb = (u16*)Cv;
  float* Cf = (float*)Cv;
  if (SPLITK > 1) Cf += (size_t)bz * (size_t)M * (size_t)N;
#pragma unroll
  for (int mt = 0; mt < MT; ++mt) {
#pragma unroll
    for (int nt = 0; nt < 4; ++nt) {
#pragma unroll
      for (int r = 0; r < 4; ++r) {
        int lrow = wm + mt * 16 + quad * 4 + r;
        int row = bx * BM + lrow;
        int col = by * 128 + wn + nt * 16 + lcol;
        float v = acc[mt][nt][r];
        if (EPI == 1) v += bias[col];
        if (EPI == 3 || EPI == 5)
          v = rstdg[row] * v - mrstdg[row] * ucol[col] + wcol[col] + bias[col];
        if (EPI == 4)
          v = rstd_s[lrow] * v - mrstd_s[lrow] * ucol[col] + wcol[col] + bias[col];
        if (EPI == 5) v = 0.5f * v * (1.f + erff(v * 0.70710678118f));
        size_t idx = (size_t)row * N + col;
        if (OUTF32) Cf[idx] = v; else Cb[idx] = f2b(v);
      }
    }
  }
}

// ---- wrappers ----
// combined prep_fold (blocks 0..959) + gemm_wc (blocks 960..967)
__global__ __launch_bounds__(256) void prep_fold_wc(
    const u16* __restrict__ WTq, const float* __restrict__ gq, const float* __restrict__ bq_,
    u16* __restrict__ WqgT, float* __restrict__ uq, float* __restrict__ wqv,
    const u16* __restrict__ WT1, const float* __restrict__ g1, const float* __restrict__ b1_,
    u16* __restrict__ W1gT, float* __restrict__ u1, float* __restrict__ w1v,
    const void* __restrict__ WkvT, const void* __restrict__ W_bottle, void* __restrict__ WcT) {
  __shared__ __align__(16) u16 lds[16384];
  int bid = blockIdx.x;
  if (bid < 960) {
    int lane = threadIdx.x & 63, w = threadIdx.x >> 6;
    const u16* WT; const float* g; const float* b; u16* WgT; float* u; float* wv; int n0;
    if (bid < 192) { WT = WTq; g = gq; b = bq_; WgT = WqgT; u = uq; wv = wqv; n0 = bid * 4; }
    else { WT = WT1; g = g1; b = b1_; WgT = W1gT; u = u1; wv = w1v; n0 = (bid - 192) * 4; }
    int n = n0 + w;
    const u16* src = WT + (size_t)n * 768;
    u16* dst = WgT + (size_t)n * 768;
    float su = 0.f, sw = 0.f;
    for (int k = lane; k < 768; k += 64) {
      float wc = b2f(src[k]);
      float wg = g[k] * wc;
      dst[k] = f2b(wg);
      su += wg;
      sw += b[k] * wc;
    }
#pragma unroll
    for (int off = 32; off >= 1; off >>= 1) {
      su += __shfl_xor(su, off, 64);
      sw += __shfl_xor(sw, off, 64);
    }
    if (lane == 0) { u[n] = su; wv[n] = sw; }
  } else {
    gemm_body<128, 1, 0, 1, 0, false, false>(lds, lds + 8192, WkvT, W_bottle, nullptr, nullptr,
                                             nullptr, nullptr, nullptr, nullptr, WcT, nullptr,
                                             128, 1024, 768, 1, 8, 1, bid - 960);
  }
}
// combined kv (blocks 0..255, f32 A + in-GEMM LN stats) + q (blocks 256..447)
__global__ __launch_bounds__(256) void gemm_kvq(
    const void* Akv, const void* Bkv, const float* biaskv,
    const float* ui, const float* wi, void* Ckv, u16* VTout,
    const void* Aq, const void* Bq, const float* biasq, const float* rstdq,
    const float* mrstdq, const float* uq, const float* wqv, void* Cq) {
  __shared__ __align__(16) u16 lds[32768];
  int bid = blockIdx.x;
  if (bid < 256) {
    // 2-phase: A region 2x4096 u16 at lds[0..8192), B region 2x4096 at lds[8192..16384)
    gemm_body<128, 1, 1, 0, 4, false, true>(lds, lds + 8192, Akv, Bkv, biaskv, nullptr, nullptr,
                                            ui, wi, nullptr, Ckv, VTout,
                                            32768, 128, 1024, 256, 1, 1, bid);
  } else {
    // PURE ring-4: A 4x2048 u16 at lds[0..8192), B 4x4096 at lds[8192..24576)
    gemm_body<64, 1, 0, 0, 3, false, false>(lds, lds + 8192, Aq, Bq, biasq, rstdq, mrstdq,
                                            uq, wqv, nullptr, Cq, nullptr,
                                            2048, 768, 768, 32, 6, 1, bid - 256);
  }
}
// out-proj with fused 4-way attn merge in A-load
__global__ __launch_bounds__(256) void gemm_o(const void* Av, const void* Bv, const float* bias,
                                              const float* lpart, void* Cv) {
  __shared__ __align__(16) u16 lds[12288];
  int vlid = ((int)blockIdx.y) * 32 + (int)blockIdx.x;
  gemm_body<64, 1, 2, 0, 1, false, false>(lds, lds + 4096, Av, Bv, bias, nullptr, nullptr,
                                          nullptr, nullptr, lpart, Cv, nullptr,
                                          2048, 768, 768, 32, 6, 1, vlid);
}
__global__ __launch_bounds__(256) void gemm_w1(const void* Av, const void* Bv, const float* bias,
                                               const float* rstdg, const float* mrstdg,
                                               const float* ucol, const float* wcol, void* Cv) {
  __shared__ __align__(16) u16 lds[32768];
  int vlid = ((int)blockIdx.y) * 16 + (int)blockIdx.x;
  gemm_body<128, 1, 0, 0, 5, false, false>(lds, lds + 16384, Av, Bv, bias, rstdg, mrstdg,
                                           ucol, wcol, nullptr, Cv, nullptr,
                                           2048, 3072, 768, 16, 24, 1, vlid);
}
__global__ __launch_bounds__(256) void gemm_w2(const void* Av, const void* Bv, void* Cv) {
  __shared__ __align__(16) u16 lds[32768];
  int vlid = (((int)blockIdx.z) * 6 + (int)blockIdx.y) * 16 + (int)blockIdx.x;
  gemm_body<128, 2, 0, 0, 0, true, false>(lds, lds + 16384, Av, Bv, nullptr, nullptr, nullptr,
                                          nullptr, nullptr, nullptr, Cv, nullptr,
                                          2048, 768, 3072, 16, 6, 2, vlid);
}

// ---------------- split-K merge for W2: out = p0 + p1 + h + b2 ----------------
__global__ __launch_bounds__(256) void w2_merge(const float* __restrict__ part,
                                                const float* __restrict__ hf,
                                                const float* __restrict__ b2,
                                                float* __restrict__ out) {
  int idx = blockIdx.x * 256 + threadIdx.x;
  f32x4 p0 = ((const f32x4*)part)[idx];
  f32x4 p1 = ((const f32x4*)part)[idx + 393216];
  f32x4 h = ((const f32x4*)hf)[idx];
  f32x4 bb = ((const f32x4*)b2)[idx % 192];
  f32x4 o;
#pragma unroll
  for (int i = 0; i < 4; ++i) o[i] = p0[i] + p1[i] + h[i] + bb[i];
  ((f32x4*)out)[idx] = o;
}

// ---------------- flash attention, MQA (1 head/block), j-split=4 ----------------
__global__ __launch_bounds__(256) void attn_kernel(const u16* __restrict__ qbuf,
                                                   const u16* __restrict__ kb,
                                                   const u16* __restrict__ VT,
                                                   float* __restrict__ Opart,
                                                   float* __restrict__ lpart) {
  __shared__ __align__(16) u16 k_lds[2][64 * 72];
  __shared__ __align__(16) u16 vt_lds[2][64 * 72];
  __shared__ __align__(16) u16 p_lds[4 * 16 * 72];
  int lid = ((int)blockIdx.z * 12 + (int)blockIdx.y) * 4 + (int)blockIdx.x;
  int wid = (lid & 7) * 192 + (lid >> 3);  // nwg=1536, bijective
  int bi = wid & 3;
  int h = (wid >> 2) % 12;
  int z = wid / 48;
  int b = z >> 2, s = z & 3;
  int t = threadIdx.x;
  int wave = t >> 6, lane = t & 63, quad = lane >> 4, lcol = lane & 15;
  int i0 = bi * 64 + wave * 16;
  const u16* qrow = qbuf + ((size_t)(b * 256 + i0 + lcol) * 768 + h * 64 + quad * 8);
  bf16x8 qf0 = *(const bf16x8*)qrow;
  bf16x8 qf1 = *(const bf16x8*)(qrow + 32);
  float l_r[4] = {0.f, 0.f, 0.f, 0.f};
  f32x4 oacc[4];
#pragma unroll
  for (int nt = 0; nt < 4; ++nt) oacc[nt] = (f32x4){0.f, 0.f, 0.f, 0.f};
  int sr = t >> 2, sc = (t & 3) * 16;
  const u16* kbase = kb + (size_t)b * 4096 * 64;
  const u16* vtbase = VT + (size_t)b * 64 * 4096;
  u16* pw = &p_lds[wave * 16 * 72];

  uint4 kr0, kr1, vr0, vr1;
  auto stage_load = [&](int jt) {
    int j0 = s * 1024 + jt * 64;
    const u16* krow = kbase + (size_t)(j0 + sr) * 64 + sc;
    kr0 = *(const uint4*)(krow);
    kr1 = *(const uint4*)(krow + 8);
    const u16* vrow = vtbase + (size_t)sr * 4096 + j0 + sc;
    vr0 = *(const uint4*)(vrow);
    vr1 = *(const uint4*)(vrow + 8);
  };
  auto stage_store = [&](int buf) {
    *(uint4*)&k_lds[buf][sr * 72 + sc] = kr0;
    *(uint4*)&k_lds[buf][sr * 72 + sc + 8] = kr1;
    *(uint4*)&vt_lds[buf][sr * 72 + sc] = vr0;
    *(uint4*)&vt_lds[buf][sr * 72 + sc + 8] = vr1;
  };

  stage_load(0);
  stage_store(0);
  phase_barrier();
  int cur = 0;
  for (int jt = 0; jt < 16; ++jt) {
    bool more = jt + 1 < 16;
    if (more) stage_load(jt + 1);

    f32x4 sc4[4];
#pragma unroll
    for (int nt = 0; nt < 4; ++nt) sc4[nt] = (f32x4){0.f, 0.f, 0.f, 0.f};
    __builtin_amdgcn_s_setprio(1);
#pragma unroll
    for (int nt = 0; nt < 4; ++nt) {
      bf16x8 kb0 = *(const bf16x8*)&k_lds[cur][(nt * 16 + lcol) * 72 + quad * 8];
      bf16x8 kb1 = *(const bf16x8*)&k_lds[cur][(nt * 16 + lcol) * 72 + 32 + quad * 8];
      sc4[nt] = __builtin_amdgcn_mfma_f32_16x16x32_bf16(qf0, kb0, sc4[nt], 0, 0, 0);
      sc4[nt] = __builtin_amdgcn_mfma_f32_16x16x32_bf16(qf1, kb1, sc4[nt], 0, 0, 0);
    }
    __builtin_amdgcn_s_setprio(0);
#pragma unroll
    for (int r = 0; r < 4; ++r) {
      float rsum = 0.f;
#pragma unroll
      for (int nt = 0; nt < 4; ++nt) {
        float p = __expf(sc4[nt][r] * 0.125f);
        sc4[nt][r] = p;
        rsum += p;
      }
      rsum += __shfl_xor(rsum, 1, 64);
      rsum += __shfl_xor(rsum, 2, 64);
      rsum += __shfl_xor(rsum, 4, 64);
      rsum += __shfl_xor(rsum, 8, 64);
      l_r[r] += rsum;
      uint32_t pk01 = cvt_pk_bf16(sc4[0][r], sc4[1][r]);
      uint32_t pk23 = cvt_pk_bf16(sc4[2][r], sc4[3][r]);
      int prow = (quad * 4 + r) * 72 + lcol;
      pw[prow] = (u16)(pk01 & 0xffff);
      pw[prow + 16] = (u16)(pk01 >> 16);
      pw[prow + 32] = (u16)(pk23 & 0xffff);
      pw[prow + 48] = (u16)(pk23 >> 16);
    }
    __builtin_amdgcn_s_setprio(1);
#pragma unroll
    for (int ks = 0; ks < 2; ++ks) {
      bf16x8 pa = *(const bf16x8*)&pw[lcol * 72 + ks * 32 + quad * 8];
#pragma unroll
      for (int nt = 0; nt < 4; ++nt) {
        bf16x8 vb = *(const bf16x8*)&vt_lds[cur][(nt * 16 + lcol) * 72 + ks * 32 + quad * 8];
        oacc[nt] = __builtin_amdgcn_mfma_f32_16x16x32_bf16(pa, vb, oacc[nt], 0, 0, 0);
      }
    }
    __builtin_amdgcn_s_setprio(0);
    if (more) stage_store(cur ^ 1);
    phase_barrier();
    cur ^= 1;
  }
  size_t base = ((size_t)z * 12 + h) * 256;
#pragma unroll
  for (int r = 0; r < 4; ++r) {
    int row = bi * 64 + wave * 16 + quad * 4 + r;
#pragma unroll
    for (int nt = 0; nt < 4; ++nt)
      Opart[(base + row) * 64 + nt * 16 + lcol] = oacc[nt][r];
    if (lcol == 0) lpart[base + row] = l_r[r];
  }
}

// ---------------- launch ----------------
extern "C" void kernel_launch(void* const* d_in, const int* in_sizes, int n_in, void* d_out,
                              int out_size, void* d_ws, size_t ws_size, hipStream_t stream) {
  (void)in_sizes; (void)n_in; (void)out_size; (void)ws_size;
  const float* hs = (const float*)d_in[0];
  const float* imgf = (const float*)d_in[1];
  const float* ln_img_g = (const float*)d_in[2];
  const float* ln_img_b = (const float*)d_in[3];
  const float* W_bottle = (const float*)d_in[4];
  const float* ln_h_g = (const float*)d_in[5];
  const float* ln_h_b = (const float*)d_in[6];
  const float* Wq = (const float*)d_in[7];
  const float* bq = (const float*)d_in[8];
  const float* Wkv = (const float*)d_in[9];
  const float* bkv = (const float*)d_in[10];
  const float* Wo = (const float*)d_in[11];
  const float* bo = (const float*)d_in[12];
  const float* ln_ao_g = (const float*)d_in[13];
  const float* ln_ao_b = (const float*)d_in[14];
  const float* gatep = (const float*)d_in[15];
  const float* ln_f_g = (const float*)d_in[16];
  const float* ln_f_b = (const float*)d_in[17];
  const float* W1 = (const float*)d_in[18];
  const float* b1 = (const float*)d_in[19];
  const float* W2 = (const float*)d_in[20];
  const float* b2 = (const float*)d_in[21];

  char* sc = (char*)d_ws;
  auto alloc = [&](size_t bytes) {
    char* p = sc;
    sc += (bytes + 63) & ~(size_t)63;
    return p;
  };
  u16* WTq = (u16*)alloc(768 * 768 * 2);
  u16* WTo = (u16*)alloc(768 * 768 * 2);
  u16* WT1 = (u16*)alloc(3072 * 768 * 2);
  u16* WT2 = (u16*)alloc(768 * 3072 * 2);
  u16* WkvT = (u16*)alloc(128 * 768 * 2);
  u16* WcT = (u16*)alloc(128 * 1024 * 2);
  u16* WgT = (u16*)alloc(128 * 1024 * 2);
  u16* WqgT = (u16*)alloc(768 * 768 * 2);
  u16* W1gT = (u16*)alloc(3072 * 768 * 2);
  float* ucol = (float*)alloc(128 * 4);
  float* wcol = (float*)alloc(128 * 4);
  float* uq = (float*)alloc(768 * 4);
  float* wq = (float*)alloc(768 * 4);
  float* u1 = (float*)alloc(3072 * 4);
  float* w1c = (float*)alloc(3072 * 4);
  float* rstdq = (float*)alloc(2048 * 4);
  float* mrstdq = (float*)alloc(2048 * 4);
  float* rstdh = (float*)alloc(2048 * 4);
  float* mrstdh = (float*)alloc(2048 * 4);
  u16* hs16 = (u16*)alloc(2048 * 768 * 2);
  u16* kb = (u16*)alloc((size_t)32768 * 64 * 2);
  u16* VT = (u16*)alloc((size_t)8 * 64 * 4096 * 2);
  u16* qb = (u16*)alloc(2048 * 768 * 2);
  u16* ao = (u16*)alloc(2048 * 768 * 2);
  u16* hbuf = (u16*)alloc(2048 * 768 * 2);
  float* hf32 = (float*)alloc(2048 * 768 * 4);
  u16* actb = (u16*)alloc((size_t)2048 * 3072 * 2);
  float* Opart = (float*)alloc((size_t)32 * 12 * 256 * 64 * 4);  // attn partials; reused for W2 split-K
  float* lpart = (float*)alloc((size_t)32 * 12 * 256 * 4);

  // 1. transposes + hs rowprep (img conversion pass ELIMINATED — fused into kv)
  prep_main<<<6368, 256, 0, stream>>>(Wq, Wo, W1, W2, Wkv, WTq, WTo, WT1, WT2, WkvT,
                                      hs, hs16, rstdq, mrstdq);
  // 2. q/w1 LN weight folds + WcT GEMM (co-launched)
  prep_fold_wc<<<968, 256, 0, stream>>>(WTq, ln_h_g, ln_h_b, WqgT, uq, wq,
                                        WT1, ln_f_g, ln_f_b, W1gT, u1, w1c,
                                        WkvT, W_bottle, WcT);
  // 3. img LN weight fold
  prep_wg<<<32, 256, 0, stream>>>(WcT, ln_img_g, ln_img_b, WgT, ucol, wcol, 1024);
  // 4. kv (f32 A, in-GEMM LN stats) + q co-launched (448 blocks)
  gemm_kvq<<<448, 256, 0, stream>>>(imgf, WgT, bkv, ucol, wcol, kb, VT,
                                    hs16, WqgT, bq, rstdq, mrstdq, uq, wq, qb);
  // 5. attention (1 head/block, j-split=4)
  attn_kernel<<<dim3(4, 12, 32), 256, 0, stream>>>(qb, kb, VT, Opart, lpart);
  // 6. out proj with fused 4-way merge
  gemm_o<<<dim3(32, 6), 256, 0, stream>>>(Opart, WTo, bo, lpart, ao);
  // 7. h = hs + sigmoid(gate)*LN(ao)
  ln_res<<<512, 256, 0, stream>>>(ao, ln_ao_g, ln_ao_b, hs, gatep, hf32, hbuf, rstdh, mrstdh);
  // 8. act = gelu(LN(h) @ W1 + b1)
  gemm_w1<<<dim3(16, 24), 256, 0, stream>>>(hbuf, W1gT, b1, rstdh, mrstdh, u1, w1c, actb);
  // 9. W2 split-K=2 partials
  gemm_w2<<<dim3(16, 6, 2), 256, 0, stream>>>(actb, WT2, Opart);
  // 10. final merge
  w2_merge<<<1536, 256, 0, stream>>>(Opart, hf32, b2, (float*)d_out);
}